// Round 3
// baseline (330.888 us; speedup 1.0000x reference)
//
#include <hip/hip_runtime.h>
#include <stdint.h>

typedef short bf16x8 __attribute__((ext_vector_type(8)));
typedef float f32x4 __attribute__((ext_vector_type(4)));

#define T_M   512
#define ML_   1536
#define LSEQ  1568
#define NHEAD 12
#define DHEAD 64
#define CDIM  768
#define NSEG  8
#define MROWS 6272  // B*L
#define CQK   1536  // q|k concat row stride
#define VTN   6272  // vt row length
#define NX4   1204224  // MROWS*CDIM/4
#define NW4   147456   // CDIM*CDIM/4
#define NWE   589824   // CDIM*CDIM

__device__ __forceinline__ unsigned short f2bf(float f) {
  unsigned u = __float_as_uint(f);
  u += 0x7fffu + ((u >> 16) & 1u);  // RNE
  return (unsigned short)(u >> 16);
}

__device__ __forceinline__ void gll16(const void* g, void* l) {
  auto* lp = reinterpret_cast<__attribute__((address_space(3))) unsigned int*>(
      reinterpret_cast<uintptr_t>(l));
  auto* gp = reinterpret_cast<const __attribute__((address_space(1))) unsigned int*>(
      reinterpret_cast<uintptr_t>(g));
  __builtin_amdgcn_global_load_lds(gp, lp, 16, 0, 0);
}

__device__ __forceinline__ f32x4 mfma16(bf16x8 a, bf16x8 b, f32x4 c) {
  return __builtin_amdgcn_mfma_f32_16x16x32_bf16(a, b, c, 0, 0, 0);
}

// Single fused f32->bf16 convert for x, Wq, Wk, Wv, Wp.
__global__ __launch_bounds__(256) void cvt5_kernel(const float* __restrict__ x,
                                                   const float* __restrict__ wq,
                                                   const float* __restrict__ wk,
                                                   const float* __restrict__ wv,
                                                   const float* __restrict__ wp,
                                                   unsigned short* __restrict__ xb,
                                                   unsigned short* __restrict__ wqkb,
                                                   unsigned short* __restrict__ wvb,
                                                   unsigned short* __restrict__ wpb) {
  int gid = blockIdx.x * 256 + threadIdx.x;
  const float* src;
  unsigned short* dst;
  int idx;
  if (gid < NX4) {
    src = x; dst = xb; idx = gid;
  } else {
    int g = gid - NX4;
    int region = g / NW4;  // compile-time-constant divisor
    idx = g - region * NW4;
    if (region == 0)      { src = wq; dst = wqkb; }
    else if (region == 1) { src = wk; dst = wqkb + NWE; }
    else if (region == 2) { src = wv; dst = wvb; }
    else                  { src = wp; dst = wpb; }
  }
  float4 v = reinterpret_cast<const float4*>(src)[idx];
  ushort4 o;
  o.x = f2bf(v.x); o.y = f2bf(v.y); o.z = f2bf(v.z); o.w = f2bf(v.w);
  reinterpret_cast<ushort4*>(dst)[idx] = o;
}

// C[m,n] = sum_k A[m,k]*Bw[n,k] + bias.  A:[M,K] bf16, Bw:[N,K] bf16 (row-major).
// BM=BN=128, BK=64; 4 waves (2x2), each wave owns 64x64. XOR-swizzled LDS
// (inverse-swizzled global source for global_load_lds + swizzled ds_read).
template <int OUT_BF16, int BIAS_ROW>
__global__ __launch_bounds__(256) void gemm_bt(const unsigned short* __restrict__ A,
                                               const unsigned short* __restrict__ Bw,
                                               const float* __restrict__ bias0,
                                               const float* __restrict__ bias1, int bsplit,
                                               void* __restrict__ Cout,
                                               int M, int N, int K) {
  __shared__ char smem[32768];
  const int tid = threadIdx.x;
  const int lane = tid & 63;
  const int w = tid >> 6;
  const int m0 = blockIdx.y * 128, n0 = blockIdx.x * 128;
  const int wr = (w >> 1) * 64, wc = (w & 1) * 64;

  unsigned gaoff[4], gboff[4];
#pragma unroll
  for (int it = 0; it < 4; ++it) {
    int off = it * 4096 + tid * 16;
    int r = off >> 7;
    int cb = (off & 127) ^ ((r & 7) << 4);
    gaoff[it] = (unsigned)((m0 + r) * K * 2 + cb);
    gboff[it] = (unsigned)((n0 + r) * K * 2 + cb);
  }
  const char* Ab = (const char*)A;
  const char* Bb = (const char*)Bw;

  f32x4 acc[4][4] = {};

  for (int ks = 0; ks < K; ks += 64) {
    __syncthreads();
#pragma unroll
    for (int it = 0; it < 4; ++it) {
      gll16(Ab + gaoff[it] + ks * 2, smem + it * 4096 + tid * 16);
      gll16(Bb + gboff[it] + ks * 2, smem + 16384 + it * 4096 + tid * 16);
    }
    __syncthreads();
#pragma unroll
    for (int kk = 0; kk < 2; ++kk) {
      const int cb = kk * 64 + (lane >> 4) * 16;
      bf16x8 av[4], bv[4];
#pragma unroll
      for (int mi = 0; mi < 4; ++mi) {
        int r = wr + mi * 16 + (lane & 15);
        av[mi] = *reinterpret_cast<const bf16x8*>(smem + r * 128 + (cb ^ ((r & 7) << 4)));
      }
#pragma unroll
      for (int ni = 0; ni < 4; ++ni) {
        int r = wc + ni * 16 + (lane & 15);
        bv[ni] = *reinterpret_cast<const bf16x8*>(smem + 16384 + r * 128 + (cb ^ ((r & 7) << 4)));
      }
#pragma unroll
      for (int mi = 0; mi < 4; ++mi)
#pragma unroll
        for (int ni = 0; ni < 4; ++ni)
          acc[mi][ni] = mfma16(av[mi], bv[ni], acc[mi][ni]);
    }
  }

#pragma unroll
  for (int mi = 0; mi < 4; ++mi) {
#pragma unroll
    for (int ni = 0; ni < 4; ++ni) {
      int col = n0 + wc + ni * 16 + (lane & 15);
      float bsc = BIAS_ROW ? 0.f : (col < bsplit ? bias0[col] : bias1[col - bsplit]);
#pragma unroll
      for (int reg = 0; reg < 4; ++reg) {
        int row = m0 + wr + mi * 16 + (lane >> 4) * 4 + reg;
        float v = acc[mi][ni][reg] + (BIAS_ROW ? bias0[row] : bsc);
        if (OUT_BF16)
          ((unsigned short*)Cout)[(size_t)row * N + col] = f2bf(v);
        else
          ((float*)Cout)[(size_t)row * N + col] = v;
      }
    }
  }
}

// LPT order of the 100 (qt, subtile) units, descending work (tiles per unit).
__device__ const unsigned char qorder[100] = {
    60, 61, 62, 63, 92, 93, 94, 95, 96, 97, 98, 99,   // w=25
    56, 57, 58, 59, 88, 89, 90, 91,                   // w=22
    52, 53, 54, 55, 84, 85, 86, 87,                   // w=19
    48, 49, 50, 51, 80, 81, 82, 83,                   // w=16
    44, 45, 46, 47, 76, 77, 78, 79,                   // w=13
    40, 41, 42, 43, 72, 73, 74, 75,                   // w=10
    28, 29, 30, 31,                                   // w=8
    36, 37, 38, 39, 68, 69, 70, 71, 24, 25, 26, 27,   // w=7
    20, 21, 22, 23,                                   // w=6
    16, 17, 18, 19,                                   // w=5
    32, 33, 34, 35, 64, 65, 66, 67, 12, 13, 14, 15,   // w=4
    8, 9, 10, 11,                                     // w=3
    4, 5, 6, 7,                                       // w=2
    0, 1, 2, 3};                                      // w=1

// Flash attention: 256-thread blocks = 4 INDEPENDENT waves (same q-subtile rank,
// 4 consecutive (b,h)); zero barriers. K prefetched one tile ahead; V prefetched
// before softmax so VMEM latency hides under the VALU phase. Defer-max (THR=8).
// qk: [6272][1536] bf16 (q cols 0..767, k cols 768..1535)
// vt: [768][6272] bf16  (row = h*64+d, col = b*1568+j)
// Grid: (12 bh-groups, 100 rank), 256 threads.
__global__ __launch_bounds__(256, 4) void attn_kernel(const unsigned short* __restrict__ qk,
                                                      const unsigned short* __restrict__ vt,
                                                      unsigned short* __restrict__ yb,
                                                      const int* __restrict__ seg_s,
                                                      const int* __restrict__ seg_e) {
  __shared__ char plds[4][2048];  // per-wave P [16][64] bf16, XOR-swizzled
  const int tid = threadIdx.x;
  const int lane = tid & 63;
  const int w = tid >> 6;
  const int lh = lane & 15, lg = lane >> 4;
  const int bh = blockIdx.x * 4 + w;
  const int b = bh / NHEAD, h = bh % NHEAD;
  const int qsub = qorder[blockIdx.y];
  const int qt = qsub >> 2, wsub = qsub & 3;
  const int rb_q = qt >> 3;   // 0,1,2 = motion blocks; 3 = text tile
  const int qtl = qt & 7;
  char* pw = plds[w];

  // Q fragments in registers for the whole loop (A operand: row=lh, k=lg*8..)
  int qr = qt * 64 + wsub * 16 + lh;
  if (qr >= LSEQ) qr = LSEQ - 1;
  const unsigned short* qp = qk + ((size_t)(b * LSEQ + qr) * CQK + h * DHEAD + lg * 8);
  const bf16x8 qf0 = *reinterpret_cast<const bf16x8*>(qp);
  const bf16x8 qf1 = *reinterpret_cast<const bf16x8*>(qp + 32);

  const unsigned short* kbase = qk + 768 + h * DHEAD + lg * 8;           // + row*CQK
  const unsigned short* vbase = vt + (size_t)(h * DHEAD + lh) * VTN + (size_t)b * LSEQ;

  f32x4 o[4] = {};
  float m_run[4] = {-1e30f, -1e30f, -1e30f, -1e30f};
  float l_run[4] = {0.f, 0.f, 0.f, 0.f};

  const int cnt = (rb_q == 0) ? (qtl + 1) : (rb_q < 3 ? 3 * (qtl + 1) + 1 : 25);

  // preload K fragments for kt=0 (first included tile is always 0)
  bf16x8 kc0[4], kc1[4];
#pragma unroll
  for (int nt = 0; nt < 4; ++nt) {
    const unsigned short* kp = kbase + (size_t)(b * LSEQ + nt * 16 + lh) * CQK;
    kc0[nt] = *reinterpret_cast<const bf16x8*>(kp);
    kc1[nt] = *reinterpret_cast<const bf16x8*>(kp + 32);
  }

  int kt = 0;
  for (int i = 0; i < cnt; ++i) {
    // next included tile index (clamped; last-iteration prefetch is harmless)
    int nkt;
    if (rb_q == 0 || rb_q >= 3) nkt = kt + 1;
    else if (kt >= 24) nkt = 24;
    else if ((kt & 7) < qtl) nkt = kt + 1;
    else nkt = (kt & ~7) + 8;
    if (nkt > 24) nkt = 24;

    // prefetch next K tile
    bf16x8 kn0[4], kn1[4];
#pragma unroll
    for (int nt = 0; nt < 4; ++nt) {
      int kr = nkt * 64 + nt * 16 + lh;
      if (kr >= LSEQ) kr = LSEQ - 1;
      const unsigned short* kp = kbase + (size_t)(b * LSEQ + kr) * CQK;
      kn0[nt] = *reinterpret_cast<const bf16x8*>(kp);
      kn1[nt] = *reinterpret_cast<const bf16x8*>(kp + 32);
    }
    // prefetch V fragments for current tile (needed only at PV, ~400 VALU cycles later)
    bf16x8 vf0[4], vf1[4];
#pragma unroll
    for (int dt = 0; dt < 4; ++dt) {
      const unsigned short* vp = vbase + (size_t)(dt * 16) * VTN + kt * 64 + lg * 8;
      vf0[dt] = *reinterpret_cast<const bf16x8*>(vp);
      vf1[dt] = *reinterpret_cast<const bf16x8*>(vp + 32);
    }

    // S = Q K^T
    f32x4 s[4];
#pragma unroll
    for (int nt = 0; nt < 4; ++nt) {
      f32x4 z = {};
      z = mfma16(qf0, kc0[nt], z);
      z = mfma16(qf1, kc1[nt], z);
      s[nt] = z;
    }

    // mask + scale (mask math only on partial tiles)
    const bool partial = (kt == 24) || ((rb_q < 3) && ((kt & 7) == qtl));
    if (!partial) {
#pragma unroll
      for (int nt = 0; nt < 4; ++nt)
#pragma unroll
        for (int reg = 0; reg < 4; ++reg) s[nt][reg] *= 0.125f;
    } else {
#pragma unroll
      for (int reg = 0; reg < 4; ++reg) {
        int r = qt * 64 + wsub * 16 + lg * 4 + reg;
        int f = r & 511;
#pragma unroll
        for (int nt = 0; nt < 4; ++nt) {
          int c = kt * 64 + nt * 16 + lh;
          bool ok;
          if (rb_q >= 3) {
            ok = (c < LSEQ);
          } else if (kt < 24) {
            int cbk = kt >> 3;
            int g = c - cbk * 512;
            bool strict = (rb_q == 1) ? (cbk != 0) : (cbk == 2);
            ok = strict ? (g < f) : (g <= f);
          } else {
            int tc = c - ML_;
            int j = tc >> 3, ii = tc & 7;
            bool st = (rb_q == 1) ? (j != 1) : (j != 0);
            ok = (tc < 32) && st && (f >= seg_s[b * NSEG + ii]) && (f < seg_e[b * NSEG + ii]);
          }
          s[nt][reg] = ok ? s[nt][reg] * 0.125f : -1e30f;
        }
      }
    }

    // per-row tile max (16-lane reduce)
    float mt[4];
#pragma unroll
    for (int reg = 0; reg < 4; ++reg) {
      float m = fmaxf(fmaxf(s[0][reg], s[1][reg]), fmaxf(s[2][reg], s[3][reg]));
#pragma unroll
      for (int off = 1; off < 16; off <<= 1) m = fmaxf(m, __shfl_xor(m, off));
      mt[reg] = m;
    }

    // fully-masked tile: nothing to add
    bool allmask = (mt[0] <= -1e29f) & (mt[1] <= -1e29f) & (mt[2] <= -1e29f) & (mt[3] <= -1e29f);
    if (__all(allmask)) {
#pragma unroll
      for (int nt = 0; nt < 4; ++nt) { kc0[nt] = kn0[nt]; kc1[nt] = kn1[nt]; }
      kt = nkt;
      continue;
    }

    // defer-max: skip m update + O rescale when the max barely grows (THR=8)
    bool deferok = (mt[0] <= m_run[0] + 8.f) & (mt[1] <= m_run[1] + 8.f) &
                   (mt[2] <= m_run[2] + 8.f) & (mt[3] <= m_run[3] + 8.f);
    const bool defer = __all(deferok);

#pragma unroll
    for (int reg = 0; reg < 4; ++reg) {
      float mn = defer ? m_run[reg] : fmaxf(m_run[reg], mt[reg]);
      float ps = 0.f;
#pragma unroll
      for (int nt = 0; nt < 4; ++nt) {
        float p = __expf(s[nt][reg] - mn);
        s[nt][reg] = p;
        ps += p;
      }
#pragma unroll
      for (int off = 1; off < 16; off <<= 1) ps += __shfl_xor(ps, off);
      if (defer) {
        l_run[reg] += ps;
      } else {
        float fc = __expf(m_run[reg] - mn);
        l_run[reg] = l_run[reg] * fc + ps;
        m_run[reg] = mn;
#pragma unroll
        for (int dt = 0; dt < 4; ++dt) o[dt][reg] *= fc;
      }
    }

    // write P (bf16, swizzled) — wave-private LDS, no barrier
#pragma unroll
    for (int reg = 0; reg < 4; ++reg) {
      int row = lg * 4 + reg;
      int swz = (row & 7) << 4;
#pragma unroll
      for (int nt = 0; nt < 4; ++nt) {
        int cbyte = (nt * 16 + lh) * 2;
        *reinterpret_cast<unsigned short*>(pw + row * 128 + (cbyte ^ swz)) = f2bf(s[nt][reg]);
      }
    }

    // O += P @ V (V already in registers)
#pragma unroll
    for (int jc = 0; jc < 2; ++jc) {
      int cbj = (jc * 32 + lg * 8) * 2;
      bf16x8 pf = *reinterpret_cast<const bf16x8*>(pw + lh * 128 + (cbj ^ ((lh & 7) << 4)));
#pragma unroll
      for (int dt = 0; dt < 4; ++dt)
        o[dt] = mfma16(pf, jc ? vf1[dt] : vf0[dt], o[dt]);
    }

#pragma unroll
    for (int nt = 0; nt < 4; ++nt) { kc0[nt] = kn0[nt]; kc1[nt] = kn1[nt]; }
    kt = nkt;
  }

  // normalize + write y (bf16)
#pragma unroll
  for (int reg = 0; reg < 4; ++reg) {
    int r = qt * 64 + wsub * 16 + lg * 4 + reg;
    if (r >= LSEQ) continue;
    float inv = 1.0f / l_run[reg];
#pragma unroll
    for (int dt = 0; dt < 4; ++dt) {
      float v = o[dt][reg] * inv;
      yb[(size_t)(b * LSEQ + r) * CDIM + h * DHEAD + dt * 16 + lh] = f2bf(v);
    }
  }
}

extern "C" void kernel_launch(void* const* d_in, const int* in_sizes, int n_in,
                              void* d_out, int out_size, void* d_ws, size_t ws_size,
                              hipStream_t stream) {
  (void)in_sizes; (void)n_in; (void)out_size;
  const float* x  = (const float*)d_in[0];
  const float* Wq = (const float*)d_in[1];
  const float* bq = (const float*)d_in[2];
  const float* Wk = (const float*)d_in[3];
  const float* bk = (const float*)d_in[4];
  const float* Wv = (const float*)d_in[5];
  const float* bv = (const float*)d_in[6];
  const float* Wp = (const float*)d_in[7];
  const float* bp = (const float*)d_in[8];
  const int* seg_s = (const int*)d_in[9];
  const int* seg_e = (const int*)d_in[10];

  const size_t NX = (size_t)MROWS * CDIM;  // 4,816,896
  const size_t NW = (size_t)CDIM * CDIM;   // 589,824
  const size_t need = (NX * 5 + NW * 4) * 2;
  if (ws_size < need) return;

  unsigned short* xb    = (unsigned short*)d_ws;
  unsigned short* wqkb  = xb + NX;          // [1536][768] (Wq rows, then Wk rows)
  unsigned short* wvb   = wqkb + 2 * NW;
  unsigned short* wpb   = wvb + NW;
  unsigned short* qkbuf = wpb + NW;         // [6272][1536]
  unsigned short* vtbuf = qkbuf + 2 * NX;   // [768][6272]
  unsigned short* ybuf  = vtbuf + NX;       // MUST follow vtbuf (tiny masked OOB reads land here)

  cvt5_kernel<<<(NX4 + 4 * NW4) / 256, 256, 0, stream>>>(x, Wq, Wk, Wv, Wp,
                                                         xb, wqkb, wvb, wpb);

  // Q|K fused projection: [6272][1536]
  gemm_bt<1, 0><<<dim3(CQK / 128, MROWS / 128), 256, 0, stream>>>(
      xb, wqkb, bq, bk, 768, qkbuf, MROWS, CQK, CDIM);
  // V^T directly via swapped operands: vt[i][m] = sum_k Wv[i,k] x[m,k] + bv[i]
  gemm_bt<1, 1><<<dim3(MROWS / 128, CDIM / 128), 256, 0, stream>>>(
      wvb, xb, bv, bv, 0, vtbuf, CDIM, MROWS, CDIM);

  attn_kernel<<<dim3(12, 100), 256, 0, stream>>>(qkbuf, vtbuf, ybuf, seg_s, seg_e);

  gemm_bt<0, 0><<<dim3(CDIM / 128, MROWS / 128), 256, 0, stream>>>(
      ybuf, wpb, bp, bp, 1 << 30, d_out, MROWS, CDIM, CDIM);
}

// Round 4
// 242.830 us; speedup vs baseline: 1.3626x; 1.3626x over previous
//
#include <hip/hip_runtime.h>
#include <stdint.h>

typedef short bf16x8 __attribute__((ext_vector_type(8)));
typedef float f32x4 __attribute__((ext_vector_type(4)));

#define T_M   512
#define ML_   1536
#define LSEQ  1568
#define NHEAD 12
#define DHEAD 64
#define CDIM  768
#define NSEG  8
#define MROWS 6272  // B*L
#define CQK   1536  // q|k concat row stride
#define VTN   6272  // vt row length
#define NX4   1204224  // MROWS*CDIM/4
#define NW4   147456   // CDIM*CDIM/4
#define NWE   589824   // CDIM*CDIM
#define SCALE2 0.1803368801111244f  // 0.125 * log2(e)

__device__ __forceinline__ unsigned short f2bf(float f) {
  unsigned u = __float_as_uint(f);
  u += 0x7fffu + ((u >> 16) & 1u);  // RNE
  return (unsigned short)(u >> 16);
}

__device__ __forceinline__ void gll16(const void* g, void* l) {
  auto* lp = reinterpret_cast<__attribute__((address_space(3))) unsigned int*>(
      reinterpret_cast<uintptr_t>(l));
  auto* gp = reinterpret_cast<const __attribute__((address_space(1))) unsigned int*>(
      reinterpret_cast<uintptr_t>(g));
  __builtin_amdgcn_global_load_lds(gp, lp, 16, 0, 0);
}

__device__ __forceinline__ f32x4 mfma16(bf16x8 a, bf16x8 b, f32x4 c) {
  return __builtin_amdgcn_mfma_f32_16x16x32_bf16(a, b, c, 0, 0, 0);
}

// Single fused f32->bf16 convert for x, Wq, Wk, Wv, Wp.
__global__ __launch_bounds__(256) void cvt5_kernel(const float* __restrict__ x,
                                                   const float* __restrict__ wq,
                                                   const float* __restrict__ wk,
                                                   const float* __restrict__ wv,
                                                   const float* __restrict__ wp,
                                                   unsigned short* __restrict__ xb,
                                                   unsigned short* __restrict__ wqkb,
                                                   unsigned short* __restrict__ wvb,
                                                   unsigned short* __restrict__ wpb) {
  int gid = blockIdx.x * 256 + threadIdx.x;
  const float* src;
  unsigned short* dst;
  int idx;
  if (gid < NX4) {
    src = x; dst = xb; idx = gid;
  } else {
    int g = gid - NX4;
    int region = g / NW4;
    idx = g - region * NW4;
    if (region == 0)      { src = wq; dst = wqkb; }
    else if (region == 1) { src = wk; dst = wqkb + NWE; }
    else if (region == 2) { src = wv; dst = wvb; }
    else                  { src = wp; dst = wpb; }
  }
  float4 v = reinterpret_cast<const float4*>(src)[idx];
  ushort4 o;
  o.x = f2bf(v.x); o.y = f2bf(v.y); o.z = f2bf(v.z); o.w = f2bf(v.w);
  reinterpret_cast<ushort4*>(dst)[idx] = o;
}

// C[m,n] = sum_k A[m,k]*Bw[n,k] + bias.  A:[M,K] bf16, Bw:[N,K] bf16 (row-major).
// BM=BN=128, BK=64; 4 waves (2x2), each wave owns 64x64. XOR-swizzled LDS.
template <int OUT_BF16, int BIAS_ROW>
__global__ __launch_bounds__(256) void gemm_bt(const unsigned short* __restrict__ A,
                                               const unsigned short* __restrict__ Bw,
                                               const float* __restrict__ bias0,
                                               const float* __restrict__ bias1, int bsplit,
                                               void* __restrict__ Cout,
                                               int M, int N, int K) {
  __shared__ char smem[32768];
  const int tid = threadIdx.x;
  const int lane = tid & 63;
  const int w = tid >> 6;
  const int m0 = blockIdx.y * 128, n0 = blockIdx.x * 128;
  const int wr = (w >> 1) * 64, wc = (w & 1) * 64;

  unsigned gaoff[4], gboff[4];
#pragma unroll
  for (int it = 0; it < 4; ++it) {
    int off = it * 4096 + tid * 16;
    int r = off >> 7;
    int cb = (off & 127) ^ ((r & 7) << 4);
    gaoff[it] = (unsigned)((m0 + r) * K * 2 + cb);
    gboff[it] = (unsigned)((n0 + r) * K * 2 + cb);
  }
  const char* Ab = (const char*)A;
  const char* Bb = (const char*)Bw;

  f32x4 acc[4][4] = {};

  for (int ks = 0; ks < K; ks += 64) {
    __syncthreads();
#pragma unroll
    for (int it = 0; it < 4; ++it) {
      gll16(Ab + gaoff[it] + ks * 2, smem + it * 4096 + tid * 16);
      gll16(Bb + gboff[it] + ks * 2, smem + 16384 + it * 4096 + tid * 16);
    }
    __syncthreads();
#pragma unroll
    for (int kk = 0; kk < 2; ++kk) {
      const int cb = kk * 64 + (lane >> 4) * 16;
      bf16x8 av[4], bv[4];
#pragma unroll
      for (int mi = 0; mi < 4; ++mi) {
        int r = wr + mi * 16 + (lane & 15);
        av[mi] = *reinterpret_cast<const bf16x8*>(smem + r * 128 + (cb ^ ((r & 7) << 4)));
      }
#pragma unroll
      for (int ni = 0; ni < 4; ++ni) {
        int r = wc + ni * 16 + (lane & 15);
        bv[ni] = *reinterpret_cast<const bf16x8*>(smem + 16384 + r * 128 + (cb ^ ((r & 7) << 4)));
      }
#pragma unroll
      for (int mi = 0; mi < 4; ++mi)
#pragma unroll
        for (int ni = 0; ni < 4; ++ni)
          acc[mi][ni] = mfma16(av[mi], bv[ni], acc[mi][ni]);
    }
  }

#pragma unroll
  for (int mi = 0; mi < 4; ++mi) {
#pragma unroll
    for (int ni = 0; ni < 4; ++ni) {
      int col = n0 + wc + ni * 16 + (lane & 15);
      float bsc = BIAS_ROW ? 0.f : (col < bsplit ? bias0[col] : bias1[col - bsplit]);
#pragma unroll
      for (int reg = 0; reg < 4; ++reg) {
        int row = m0 + wr + mi * 16 + (lane >> 4) * 4 + reg;
        float v = acc[mi][ni][reg] + (BIAS_ROW ? bias0[row] : bsc);
        if (OUT_BF16)
          ((unsigned short*)Cout)[(size_t)row * N + col] = f2bf(v);
        else
          ((float*)Cout)[(size_t)row * N + col] = v;
      }
    }
  }
}

// LPT order of the 100 (qt, subtile) units, descending work (tiles per unit).
__device__ const unsigned char qorder[100] = {
    60, 61, 62, 63, 92, 93, 94, 95, 96, 97, 98, 99,   // w=25
    56, 57, 58, 59, 88, 89, 90, 91,                   // w=22
    52, 53, 54, 55, 84, 85, 86, 87,                   // w=19
    48, 49, 50, 51, 80, 81, 82, 83,                   // w=16
    44, 45, 46, 47, 76, 77, 78, 79,                   // w=13
    40, 41, 42, 43, 72, 73, 74, 75,                   // w=10
    28, 29, 30, 31,                                   // w=8
    36, 37, 38, 39, 68, 69, 70, 71, 24, 25, 26, 27,   // w=7
    20, 21, 22, 23,                                   // w=6
    16, 17, 18, 19,                                   // w=5
    32, 33, 34, 35, 64, 65, 66, 67, 12, 13, 14, 15,   // w=4
    8, 9, 10, 11,                                     // w=3
    4, 5, 6, 7,                                       // w=2
    0, 1, 2, 3};                                      // w=1

// Flash attention, 1 wave per block, no barriers. R2 structure + V-prefetch,
// exp2-domain softmax, defer-max, fully-masked-tile skip.
// qk: [6272][1536] bf16 (q cols 0..767, k cols 768..1535)
// vt: [768][6272] bf16  (row = h*64+d, col = b*1568+j)
// Grid: (48 bh, 100 rank), 64 threads.
__global__ __launch_bounds__(64) void attn_kernel(const unsigned short* __restrict__ qk,
                                                  const unsigned short* __restrict__ vt,
                                                  unsigned short* __restrict__ yb,
                                                  const int* __restrict__ seg_s,
                                                  const int* __restrict__ seg_e) {
  __shared__ char pw[2048];  // wave-private P [16][64] bf16, XOR-swizzled
  const int lane = threadIdx.x;
  const int lh = lane & 15, lg = lane >> 4;
  const int bh = blockIdx.x;
  const int b = bh / NHEAD, h = bh % NHEAD;
  const int qsub = qorder[blockIdx.y];
  const int qt = qsub >> 2, wsub = qsub & 3;
  const int rb_q = qt >> 3;   // 0,1,2 = motion blocks; 3 = text tile
  const int qtl = qt & 7;

  // Q fragments in registers for the whole loop (A operand: row=lh, k=lg*8..)
  int qr = qt * 64 + wsub * 16 + lh;
  if (qr >= LSEQ) qr = LSEQ - 1;
  const unsigned short* qp = qk + ((size_t)(b * LSEQ + qr) * CQK + h * DHEAD + lg * 8);
  const bf16x8 qf0 = *reinterpret_cast<const bf16x8*>(qp);
  const bf16x8 qf1 = *reinterpret_cast<const bf16x8*>(qp + 32);

  const unsigned short* kbase = qk + 768 + h * DHEAD + lg * 8;           // + row*CQK
  const unsigned short* vbase = vt + (size_t)(h * DHEAD + lh) * VTN + (size_t)b * LSEQ;

  // per-lane segment bounds: text col index ii = (16*nt+lh)&7 = lh&7
  const int ss = seg_s[b * NSEG + (lh & 7)];
  const int se = seg_e[b * NSEG + (lh & 7)];

  f32x4 o[4] = {};
  float m_run[4] = {-1e30f, -1e30f, -1e30f, -1e30f};  // log2-domain running max
  float l_run[4] = {0.f, 0.f, 0.f, 0.f};

  for (int kt = 0; kt < 25; ++kt) {
    bool inc;
    if (rb_q >= 3) inc = true;
    else if (rb_q == 0) inc = (kt <= qtl);
    else inc = (kt == 24) || ((kt & 7) <= qtl);
    if (!inc) continue;  // block-uniform skip

    // prefetch V fragments for this tile (consumed only at PV, after softmax VALU)
    bf16x8 vf0[4], vf1[4];
#pragma unroll
    for (int dt = 0; dt < 4; ++dt) {
      const unsigned short* vp = vbase + (size_t)(dt * 16) * VTN + kt * 64 + lg * 8;
      vf0[dt] = *reinterpret_cast<const bf16x8*>(vp);
      vf1[dt] = *reinterpret_cast<const bf16x8*>(vp + 32);
    }

    // S = Q K^T  (K fragments direct from global)
    f32x4 s[4];
#pragma unroll
    for (int nt = 0; nt < 4; ++nt) {
      int kr = kt * 64 + nt * 16 + lh;
      if (kr >= LSEQ) kr = LSEQ - 1;
      const unsigned short* kp = kbase + (size_t)(b * LSEQ + kr) * CQK;
      bf16x8 k0 = *reinterpret_cast<const bf16x8*>(kp);
      bf16x8 k1 = *reinterpret_cast<const bf16x8*>(kp + 32);
      f32x4 z = {};
      z = mfma16(qf0, k0, z);
      z = mfma16(qf1, k1, z);
      s[nt] = z;
    }

    // mask + scale into log2 domain (mask math only on partial tiles)
    const bool partial = (kt == 24) || ((rb_q < 3) && ((kt & 7) == qtl));
    if (!partial) {
#pragma unroll
      for (int nt = 0; nt < 4; ++nt)
#pragma unroll
        for (int reg = 0; reg < 4; ++reg) s[nt][reg] *= SCALE2;
    } else {
#pragma unroll
      for (int reg = 0; reg < 4; ++reg) {
        int r = qt * 64 + wsub * 16 + lg * 4 + reg;
        int f = r & 511;
#pragma unroll
        for (int nt = 0; nt < 4; ++nt) {
          int c = kt * 64 + nt * 16 + lh;
          bool ok;
          if (rb_q >= 3) {
            ok = (c < LSEQ);
          } else if (kt < 24) {
            int cbk = kt >> 3;
            int g = c - cbk * 512;
            bool strict = (rb_q == 1) ? (cbk != 0) : (cbk == 2);
            ok = strict ? (g < f) : (g <= f);
          } else {
            int tc = c - ML_;
            int j = tc >> 3;
            bool st = (rb_q == 1) ? (j != 1) : (j != 0);
            ok = (tc < 32) && st && (f >= ss) && (f < se);
          }
          s[nt][reg] = ok ? s[nt][reg] * SCALE2 : -1e30f;
        }
      }
    }

    // per-row tile max (16-lane reduce)
    float mt[4];
#pragma unroll
    for (int reg = 0; reg < 4; ++reg) {
      float m = fmaxf(fmaxf(s[0][reg], s[1][reg]), fmaxf(s[2][reg], s[3][reg]));
#pragma unroll
      for (int off = 1; off < 16; off <<= 1) m = fmaxf(m, __shfl_xor(m, off));
      mt[reg] = m;
    }

    // fully-masked tile: nothing to accumulate
    bool allmask = (mt[0] <= -1e29f) & (mt[1] <= -1e29f) & (mt[2] <= -1e29f) & (mt[3] <= -1e29f);
    if (__all(allmask)) continue;

    // defer-max: skip m update + O rescale when max barely grows (2^12 headroom)
    bool deferok = (mt[0] <= m_run[0] + 12.f) & (mt[1] <= m_run[1] + 12.f) &
                   (mt[2] <= m_run[2] + 12.f) & (mt[3] <= m_run[3] + 12.f);
    const bool defer = __all(deferok);

#pragma unroll
    for (int reg = 0; reg < 4; ++reg) {
      float mn = defer ? m_run[reg] : fmaxf(m_run[reg], mt[reg]);
      float ps = 0.f;
#pragma unroll
      for (int nt = 0; nt < 4; ++nt) {
        float p = exp2f(s[nt][reg] - mn);
        s[nt][reg] = p;
        ps += p;
      }
#pragma unroll
      for (int off = 1; off < 16; off <<= 1) ps += __shfl_xor(ps, off);
      if (defer) {
        l_run[reg] += ps;
      } else {
        float fc = exp2f(m_run[reg] - mn);
        l_run[reg] = l_run[reg] * fc + ps;
        m_run[reg] = mn;
#pragma unroll
        for (int dt = 0; dt < 4; ++dt) o[dt][reg] *= fc;
      }
    }

    // write P (bf16, swizzled) — wave-private LDS, no barrier
#pragma unroll
    for (int reg = 0; reg < 4; ++reg) {
      int row = lg * 4 + reg;
      int swz = (row & 7) << 4;
#pragma unroll
      for (int nt = 0; nt < 4; ++nt) {
        int cbyte = (nt * 16 + lh) * 2;
        *reinterpret_cast<unsigned short*>(pw + row * 128 + (cbyte ^ swz)) = f2bf(s[nt][reg]);
      }
    }

    // O += P @ V (V already in registers)
#pragma unroll
    for (int jc = 0; jc < 2; ++jc) {
      int cbj = (jc * 32 + lg * 8) * 2;
      bf16x8 pf = *reinterpret_cast<const bf16x8*>(pw + lh * 128 + (cbj ^ ((lh & 7) << 4)));
#pragma unroll
      for (int dt = 0; dt < 4; ++dt)
        o[dt] = mfma16(pf, jc ? vf1[dt] : vf0[dt], o[dt]);
    }
  }

  // normalize + write y (bf16)
#pragma unroll
  for (int reg = 0; reg < 4; ++reg) {
    int r = qt * 64 + wsub * 16 + lg * 4 + reg;
    if (r >= LSEQ) continue;
    float inv = 1.0f / l_run[reg];
#pragma unroll
    for (int dt = 0; dt < 4; ++dt) {
      float v = o[dt][reg] * inv;
      yb[(size_t)(b * LSEQ + r) * CDIM + h * DHEAD + dt * 16 + lh] = f2bf(v);
    }
  }
}

extern "C" void kernel_launch(void* const* d_in, const int* in_sizes, int n_in,
                              void* d_out, int out_size, void* d_ws, size_t ws_size,
                              hipStream_t stream) {
  (void)in_sizes; (void)n_in; (void)out_size;
  const float* x  = (const float*)d_in[0];
  const float* Wq = (const float*)d_in[1];
  const float* bq = (const float*)d_in[2];
  const float* Wk = (const float*)d_in[3];
  const float* bk = (const float*)d_in[4];
  const float* Wv = (const float*)d_in[5];
  const float* bv = (const float*)d_in[6];
  const float* Wp = (const float*)d_in[7];
  const float* bp = (const float*)d_in[8];
  const int* seg_s = (const int*)d_in[9];
  const int* seg_e = (const int*)d_in[10];

  const size_t NX = (size_t)MROWS * CDIM;  // 4,816,896
  const size_t NW = (size_t)CDIM * CDIM;   // 589,824
  const size_t need = (NX * 5 + NW * 4) * 2;
  if (ws_size < need) return;

  unsigned short* xb    = (unsigned short*)d_ws;
  unsigned short* wqkb  = xb + NX;          // [1536][768] (Wq rows, then Wk rows)
  unsigned short* wvb   = wqkb + 2 * NW;
  unsigned short* wpb   = wvb + NW;
  unsigned short* qkbuf = wpb + NW;         // [6272][1536]
  unsigned short* vtbuf = qkbuf + 2 * NX;   // [768][6272]
  unsigned short* ybuf  = vtbuf + NX;       // MUST follow vtbuf (tiny masked OOB reads land here)

  cvt5_kernel<<<(NX4 + 4 * NW4) / 256, 256, 0, stream>>>(x, Wq, Wk, Wv, Wp,
                                                         xb, wqkb, wvb, wpb);

  // Q|K fused projection: [6272][1536]
  gemm_bt<1, 0><<<dim3(CQK / 128, MROWS / 128), 256, 0, stream>>>(
      xb, wqkb, bq, bk, 768, qkbuf, MROWS, CQK, CDIM);
  // V^T directly via swapped operands: vt[i][m] = sum_k Wv[i,k] x[m,k] + bv[i]
  gemm_bt<1, 1><<<dim3(MROWS / 128, CDIM / 128), 256, 0, stream>>>(
      wvb, xb, bv, bv, 0, vtbuf, CDIM, MROWS, CDIM);

  attn_kernel<<<dim3(48, 100), 64, 0, stream>>>(qkbuf, vtbuf, ybuf, seg_s, seg_e);

  gemm_bt<0, 0><<<dim3(CDIM / 128, MROWS / 128), 256, 0, stream>>>(
      ybuf, wpb, bp, bp, 1 << 30, d_out, MROWS, CDIM, CDIM);
}

// Round 5
// 207.412 us; speedup vs baseline: 1.5953x; 1.1708x over previous
//
#include <hip/hip_runtime.h>
#include <stdint.h>

typedef short bf16x8 __attribute__((ext_vector_type(8)));
typedef float f32x4 __attribute__((ext_vector_type(4)));

#define T_M   512
#define ML_   1536
#define LSEQ  1568
#define NHEAD 12
#define DHEAD 64
#define CDIM  768
#define NSEG  8
#define MROWS 6272  // B*L
#define CQK   1536  // q|k concat row stride
#define VTN   6272  // vt row length
#define NX4   1204224  // MROWS*CDIM/4
#define NW4   147456   // CDIM*CDIM/4
#define NWE   589824   // CDIM*CDIM
#define SCALE2 0.1803368801111244f  // 0.125 * log2(e)

__device__ __forceinline__ unsigned short f2bf(float f) {
  unsigned u = __float_as_uint(f);
  u += 0x7fffu + ((u >> 16) & 1u);  // RNE
  return (unsigned short)(u >> 16);
}

__device__ __forceinline__ void gll16(const void* g, void* l) {
  auto* lp = reinterpret_cast<__attribute__((address_space(3))) unsigned int*>(
      reinterpret_cast<uintptr_t>(l));
  auto* gp = reinterpret_cast<const __attribute__((address_space(1))) unsigned int*>(
      reinterpret_cast<uintptr_t>(g));
  __builtin_amdgcn_global_load_lds(gp, lp, 16, 0, 0);
}

__device__ __forceinline__ f32x4 mfma16(bf16x8 a, bf16x8 b, f32x4 c) {
  return __builtin_amdgcn_mfma_f32_16x16x32_bf16(a, b, c, 0, 0, 0);
}

// Single fused f32->bf16 convert for x, Wq, Wk, Wv, Wp.
__global__ __launch_bounds__(256) void cvt5_kernel(const float* __restrict__ x,
                                                   const float* __restrict__ wq,
                                                   const float* __restrict__ wk,
                                                   const float* __restrict__ wv,
                                                   const float* __restrict__ wp,
                                                   unsigned short* __restrict__ xb,
                                                   unsigned short* __restrict__ wqkb,
                                                   unsigned short* __restrict__ wvb,
                                                   unsigned short* __restrict__ wpb) {
  int gid = blockIdx.x * 256 + threadIdx.x;
  const float* src;
  unsigned short* dst;
  int idx;
  if (gid < NX4) {
    src = x; dst = xb; idx = gid;
  } else {
    int g = gid - NX4;
    int region = g / NW4;
    idx = g - region * NW4;
    if (region == 0)      { src = wq; dst = wqkb; }
    else if (region == 1) { src = wk; dst = wqkb + NWE; }
    else if (region == 2) { src = wv; dst = wvb; }
    else                  { src = wp; dst = wpb; }
  }
  float4 v = reinterpret_cast<const float4*>(src)[idx];
  ushort4 o;
  o.x = f2bf(v.x); o.y = f2bf(v.y); o.z = f2bf(v.z); o.w = f2bf(v.w);
  reinterpret_cast<ushort4*>(dst)[idx] = o;
}

// C[m,n] = sum_k A[m,k]*Bw[n,k] + bias.  A:[M,K] bf16, Bw:[N,K] bf16 (row-major).
// BM=BN=128, BK=64; 4 waves (2x2), each wave owns 64x64. XOR-swizzled LDS.
template <int OUT_BF16, int BIAS_ROW>
__global__ __launch_bounds__(256) void gemm_bt(const unsigned short* __restrict__ A,
                                               const unsigned short* __restrict__ Bw,
                                               const float* __restrict__ bias0,
                                               const float* __restrict__ bias1, int bsplit,
                                               void* __restrict__ Cout,
                                               int M, int N, int K) {
  __shared__ char smem[32768];
  const int tid = threadIdx.x;
  const int lane = tid & 63;
  const int w = tid >> 6;
  const int m0 = blockIdx.y * 128, n0 = blockIdx.x * 128;
  const int wr = (w >> 1) * 64, wc = (w & 1) * 64;

  unsigned gaoff[4], gboff[4];
#pragma unroll
  for (int it = 0; it < 4; ++it) {
    int off = it * 4096 + tid * 16;
    int r = off >> 7;
    int cb = (off & 127) ^ ((r & 7) << 4);
    gaoff[it] = (unsigned)((m0 + r) * K * 2 + cb);
    gboff[it] = (unsigned)((n0 + r) * K * 2 + cb);
  }
  const char* Ab = (const char*)A;
  const char* Bb = (const char*)Bw;

  f32x4 acc[4][4] = {};

  for (int ks = 0; ks < K; ks += 64) {
    __syncthreads();
#pragma unroll
    for (int it = 0; it < 4; ++it) {
      gll16(Ab + gaoff[it] + ks * 2, smem + it * 4096 + tid * 16);
      gll16(Bb + gboff[it] + ks * 2, smem + 16384 + it * 4096 + tid * 16);
    }
    __syncthreads();
#pragma unroll
    for (int kk = 0; kk < 2; ++kk) {
      const int cb = kk * 64 + (lane >> 4) * 16;
      bf16x8 av[4], bv[4];
#pragma unroll
      for (int mi = 0; mi < 4; ++mi) {
        int r = wr + mi * 16 + (lane & 15);
        av[mi] = *reinterpret_cast<const bf16x8*>(smem + r * 128 + (cb ^ ((r & 7) << 4)));
      }
#pragma unroll
      for (int ni = 0; ni < 4; ++ni) {
        int r = wc + ni * 16 + (lane & 15);
        bv[ni] = *reinterpret_cast<const bf16x8*>(smem + 16384 + r * 128 + (cb ^ ((r & 7) << 4)));
      }
#pragma unroll
      for (int mi = 0; mi < 4; ++mi)
#pragma unroll
        for (int ni = 0; ni < 4; ++ni)
          acc[mi][ni] = mfma16(av[mi], bv[ni], acc[mi][ni]);
    }
  }

#pragma unroll
  for (int mi = 0; mi < 4; ++mi) {
#pragma unroll
    for (int ni = 0; ni < 4; ++ni) {
      int col = n0 + wc + ni * 16 + (lane & 15);
      float bsc = BIAS_ROW ? 0.f : (col < bsplit ? bias0[col] : bias1[col - bsplit]);
#pragma unroll
      for (int reg = 0; reg < 4; ++reg) {
        int row = m0 + wr + mi * 16 + (lane >> 4) * 4 + reg;
        float v = acc[mi][ni][reg] + (BIAS_ROW ? bias0[row] : bsc);
        if (OUT_BF16)
          ((unsigned short*)Cout)[(size_t)row * N + col] = f2bf(v);
        else
          ((float*)Cout)[(size_t)row * N + col] = v;
      }
    }
  }
}

// LPT order of the 98 useful (qt, subtile) units, descending work.
// (ranks 98,99 = text rows >= 1568 dropped: they were pure waste)
__device__ const unsigned char qorder[98] = {
    60, 61, 62, 63, 92, 93, 94, 95, 96, 97,           // w=25
    56, 57, 58, 59, 88, 89, 90, 91,                   // w=22
    52, 53, 54, 55, 84, 85, 86, 87,                   // w=19
    48, 49, 50, 51, 80, 81, 82, 83,                   // w=16
    44, 45, 46, 47, 76, 77, 78, 79,                   // w=13
    40, 41, 42, 43, 72, 73, 74, 75,                   // w=10
    28, 29, 30, 31,                                   // w=8
    36, 37, 38, 39, 68, 69, 70, 71, 24, 25, 26, 27,   // w=7
    20, 21, 22, 23,                                   // w=6
    16, 17, 18, 19,                                   // w=5
    32, 33, 34, 35, 64, 65, 66, 67, 12, 13, 14, 15,   // w=4
    8, 9, 10, 11,                                     // w=3
    4, 5, 6, 7,                                       // w=2
    0, 1, 2, 3};                                      // w=1

// Flash attention, split-KV: 256-thread block = 4 waves on the SAME q-subtile,
// each wave takes every-4th included KV tile (max chain 25 -> 7), then one
// __syncthreads + LDS merge of the 4 partial (m,l,O). R2 per-tile body
// (inline K/V loads, low VGPR) + exp2-domain softmax + defer-max + allmask skip.
// qk: [6272][1536] bf16 (q cols 0..767, k cols 768..1535)
// vt: [768][6272] bf16  (row = h*64+d, col = b*1568+j)
// Grid: (48 bh, 98 rank), 256 threads.
__global__ __launch_bounds__(256, 5) void attn_kernel(const unsigned short* __restrict__ qk,
                                                      const unsigned short* __restrict__ vt,
                                                      unsigned short* __restrict__ yb,
                                                      const int* __restrict__ seg_s,
                                                      const int* __restrict__ seg_e) {
  __shared__ char plds[4][2048];       // per-wave P [16][64] bf16, XOR-swizzled
  __shared__ float olds[4][16][64];    // partial O per wave
  __shared__ float mlds[4][16], llds[4][16];
  const int tid = threadIdx.x;
  const int lane = tid & 63;
  const int w = tid >> 6;
  const int lh = lane & 15, lg = lane >> 4;
  const int bh = blockIdx.x;
  const int b = bh / NHEAD, h = bh % NHEAD;
  const int qsub = qorder[blockIdx.y];
  const int qt = qsub >> 2, wsub = qsub & 3;
  const int rb_q = qt >> 3;   // 0,1,2 = motion blocks; 3 = text tile
  const int qtl = qt & 7;
  char* pw = plds[w];

  // Q fragments in registers (A operand: row=lh, k=lg*8..)
  int qr = qt * 64 + wsub * 16 + lh;
  if (qr >= LSEQ) qr = LSEQ - 1;
  const unsigned short* qp = qk + ((size_t)(b * LSEQ + qr) * CQK + h * DHEAD + lg * 8);
  const bf16x8 qf0 = *reinterpret_cast<const bf16x8*>(qp);
  const bf16x8 qf1 = *reinterpret_cast<const bf16x8*>(qp + 32);

  const unsigned short* kbase = qk + 768 + h * DHEAD + lg * 8;           // + row*CQK
  const unsigned short* vbase = vt + (size_t)(h * DHEAD + lh) * VTN + (size_t)b * LSEQ;

  // per-lane segment bounds: text col index ii = (16*nt+lh)&7 = lh&7
  const int ss = seg_s[b * NSEG + (lh & 7)];
  const int se = seg_e[b * NSEG + (lh & 7)];

  f32x4 o[4] = {};
  float m_run[4] = {-1e30f, -1e30f, -1e30f, -1e30f};  // log2-domain
  float l_run[4] = {0.f, 0.f, 0.f, 0.f};

  const int per = qtl + 1;
  const int cnt = (rb_q == 0) ? per : (rb_q < 3 ? 3 * per + 1 : 25);

  // this wave handles included-tile ranks w, w+4, w+8, ...
  for (int idx = w; idx < cnt; idx += 4) {
    int kt;
    if (rb_q == 0 || rb_q >= 3) kt = idx;
    else if (idx >= 3 * per) kt = 24;
    else {
      int cbk = (idx >= 2 * per) ? 2 : (idx >= per ? 1 : 0);
      kt = cbk * 8 + (idx - cbk * per);
    }

    // S = Q K^T  (K fragments direct from global)
    f32x4 s[4];
#pragma unroll
    for (int nt = 0; nt < 4; ++nt) {
      int kr = kt * 64 + nt * 16 + lh;
      if (kr >= LSEQ) kr = LSEQ - 1;
      const unsigned short* kp = kbase + (size_t)(b * LSEQ + kr) * CQK;
      bf16x8 k0 = *reinterpret_cast<const bf16x8*>(kp);
      bf16x8 k1 = *reinterpret_cast<const bf16x8*>(kp + 32);
      f32x4 z = {};
      z = mfma16(qf0, k0, z);
      z = mfma16(qf1, k1, z);
      s[nt] = z;
    }

    // mask + scale into log2 domain (mask math only on partial tiles)
    const bool partial = (kt == 24) || ((rb_q < 3) && ((kt & 7) == qtl));
    if (!partial) {
#pragma unroll
      for (int nt = 0; nt < 4; ++nt)
#pragma unroll
        for (int reg = 0; reg < 4; ++reg) s[nt][reg] *= SCALE2;
    } else {
#pragma unroll
      for (int reg = 0; reg < 4; ++reg) {
        int r = qt * 64 + wsub * 16 + lg * 4 + reg;
        int f = r & 511;
#pragma unroll
        for (int nt = 0; nt < 4; ++nt) {
          int c = kt * 64 + nt * 16 + lh;
          bool ok;
          if (rb_q >= 3) {
            ok = (c < LSEQ);
          } else if (kt < 24) {
            int cbk = kt >> 3;
            int g = c - cbk * 512;
            bool strict = (rb_q == 1) ? (cbk != 0) : (cbk == 2);
            ok = strict ? (g < f) : (g <= f);
          } else {
            int tc = c - ML_;
            int j = tc >> 3;
            bool st = (rb_q == 1) ? (j != 1) : (j != 0);
            ok = (tc < 32) && st && (f >= ss) && (f < se);
          }
          s[nt][reg] = ok ? s[nt][reg] * SCALE2 : -1e30f;
        }
      }
    }

    // per-row tile max (16-lane reduce)
    float mt[4];
#pragma unroll
    for (int reg = 0; reg < 4; ++reg) {
      float m = fmaxf(fmaxf(s[0][reg], s[1][reg]), fmaxf(s[2][reg], s[3][reg]));
#pragma unroll
      for (int off = 1; off < 16; off <<= 1) m = fmaxf(m, __shfl_xor(m, off));
      mt[reg] = m;
    }

    // fully-masked tile: nothing to accumulate
    bool allmask = (mt[0] <= -1e29f) & (mt[1] <= -1e29f) & (mt[2] <= -1e29f) & (mt[3] <= -1e29f);
    if (__all(allmask)) continue;

    // defer-max (2^12 headroom in log2 domain)
    bool deferok = (mt[0] <= m_run[0] + 12.f) & (mt[1] <= m_run[1] + 12.f) &
                   (mt[2] <= m_run[2] + 12.f) & (mt[3] <= m_run[3] + 12.f);
    const bool defer = __all(deferok);

#pragma unroll
    for (int reg = 0; reg < 4; ++reg) {
      float mn = defer ? m_run[reg] : fmaxf(m_run[reg], mt[reg]);
      float ps = 0.f;
#pragma unroll
      for (int nt = 0; nt < 4; ++nt) {
        float p = exp2f(s[nt][reg] - mn);
        s[nt][reg] = p;
        ps += p;
      }
#pragma unroll
      for (int off = 1; off < 16; off <<= 1) ps += __shfl_xor(ps, off);
      if (defer) {
        l_run[reg] += ps;
      } else {
        float fc = exp2f(m_run[reg] - mn);
        l_run[reg] = l_run[reg] * fc + ps;
        m_run[reg] = mn;
#pragma unroll
        for (int dt = 0; dt < 4; ++dt) o[dt][reg] *= fc;
      }
    }

    // write P (bf16, swizzled) — wave-private LDS, no barrier
#pragma unroll
    for (int reg = 0; reg < 4; ++reg) {
      int row = lg * 4 + reg;
      int swz = (row & 7) << 4;
#pragma unroll
      for (int nt = 0; nt < 4; ++nt) {
        int cbyte = (nt * 16 + lh) * 2;
        *reinterpret_cast<unsigned short*>(pw + row * 128 + (cbyte ^ swz)) = f2bf(s[nt][reg]);
      }
    }

    // O += P @ V (V^T fragments direct from global)
#pragma unroll
    for (int jc = 0; jc < 2; ++jc) {
      int cbj = (jc * 32 + lg * 8) * 2;
      bf16x8 pf = *reinterpret_cast<const bf16x8*>(pw + lh * 128 + (cbj ^ ((lh & 7) << 4)));
#pragma unroll
      for (int dt = 0; dt < 4; ++dt) {
        const unsigned short* vp = vbase + (size_t)(dt * 16) * VTN + kt * 64 + jc * 32 + lg * 8;
        bf16x8 vf = *reinterpret_cast<const bf16x8*>(vp);
        o[dt] = mfma16(pf, vf, o[dt]);
      }
    }
  }

  // ---- merge the 4 splits ----
  if (lh == 0) {
#pragma unroll
    for (int reg = 0; reg < 4; ++reg) {
      mlds[w][lg * 4 + reg] = m_run[reg];
      llds[w][lg * 4 + reg] = l_run[reg];
    }
  }
#pragma unroll
  for (int reg = 0; reg < 4; ++reg)
#pragma unroll
    for (int dt = 0; dt < 4; ++dt)
      olds[w][lg * 4 + reg][dt * 16 + lh] = o[dt][reg];

  __syncthreads();

  if (w == 0) {
#pragma unroll
    for (int reg = 0; reg < 4; ++reg) {
      int row = lg * 4 + reg;
      int r = qt * 64 + wsub * 16 + row;
      if (r >= LSEQ) continue;
      float ms[4];
      float M = -1e30f;
#pragma unroll
      for (int sidx = 0; sidx < 4; ++sidx) {
        ms[sidx] = mlds[sidx][row];
        M = fmaxf(M, ms[sidx]);
      }
      float wsc[4];
      float lsum = 0.f;
#pragma unroll
      for (int sidx = 0; sidx < 4; ++sidx) {
        wsc[sidx] = exp2f(ms[sidx] - M);
        lsum += llds[sidx][row] * wsc[sidx];
      }
      float inv = 1.0f / lsum;
#pragma unroll
      for (int dt = 0; dt < 4; ++dt) {
        int col = dt * 16 + lh;
        float acc = 0.f;
#pragma unroll
        for (int sidx = 0; sidx < 4; ++sidx)
          acc += olds[sidx][row][col] * wsc[sidx];
        yb[(size_t)(b * LSEQ + r) * CDIM + h * DHEAD + col] = f2bf(acc * inv);
      }
    }
  }
}

extern "C" void kernel_launch(void* const* d_in, const int* in_sizes, int n_in,
                              void* d_out, int out_size, void* d_ws, size_t ws_size,
                              hipStream_t stream) {
  (void)in_sizes; (void)n_in; (void)out_size;
  const float* x  = (const float*)d_in[0];
  const float* Wq = (const float*)d_in[1];
  const float* bq = (const float*)d_in[2];
  const float* Wk = (const float*)d_in[3];
  const float* bk = (const float*)d_in[4];
  const float* Wv = (const float*)d_in[5];
  const float* bv = (const float*)d_in[6];
  const float* Wp = (const float*)d_in[7];
  const float* bp = (const float*)d_in[8];
  const int* seg_s = (const int*)d_in[9];
  const int* seg_e = (const int*)d_in[10];

  const size_t NX = (size_t)MROWS * CDIM;  // 4,816,896
  const size_t NW = (size_t)CDIM * CDIM;   // 589,824
  const size_t need = (NX * 5 + NW * 4) * 2;
  if (ws_size < need) return;

  unsigned short* xb    = (unsigned short*)d_ws;
  unsigned short* wqkb  = xb + NX;          // [1536][768] (Wq rows, then Wk rows)
  unsigned short* wvb   = wqkb + 2 * NW;
  unsigned short* wpb   = wvb + NW;
  unsigned short* qkbuf = wpb + NW;         // [6272][1536]
  unsigned short* vtbuf = qkbuf + 2 * NX;   // [768][6272]
  unsigned short* ybuf  = vtbuf + NX;       // MUST follow vtbuf (tiny masked OOB reads land here)

  cvt5_kernel<<<(NX4 + 4 * NW4) / 256, 256, 0, stream>>>(x, Wq, Wk, Wv, Wp,
                                                         xb, wqkb, wvb, wpb);

  // Q|K fused projection: [6272][1536]
  gemm_bt<1, 0><<<dim3(CQK / 128, MROWS / 128), 256, 0, stream>>>(
      xb, wqkb, bq, bk, 768, qkbuf, MROWS, CQK, CDIM);
  // V^T directly via swapped operands: vt[i][m] = sum_k Wv[i,k] x[m,k] + bv[i]
  gemm_bt<1, 1><<<dim3(MROWS / 128, CDIM / 128), 256, 0, stream>>>(
      wvb, xb, bv, bv, 0, vtbuf, CDIM, MROWS, CDIM);

  attn_kernel<<<dim3(48, 98), 256, 0, stream>>>(qkbuf, vtbuf, ybuf, seg_s, seg_e);

  gemm_bt<0, 0><<<dim3(CDIM / 128, MROWS / 128), 256, 0, stream>>>(
      ybuf, wpb, bp, bp, 1 << 30, d_out, MROWS, CDIM, CDIM);
}

// Round 6
// 185.665 us; speedup vs baseline: 1.7822x; 1.1171x over previous
//
#include <hip/hip_runtime.h>
#include <hip/hip_bf16.h>
#include <stdint.h>

typedef short bf16x8 __attribute__((ext_vector_type(8)));
typedef float f32x4 __attribute__((ext_vector_type(4)));

#define T_M   512
#define ML_   1536
#define LSEQ  1568
#define NHEAD 12
#define DHEAD 64
#define CDIM  768
#define NSEG  8
#define MROWS 6272  // B*L
#define CQK   1536  // q|k concat row stride
#define VTN   6272  // vt row length
#define NX4   1204224  // MROWS*CDIM/4
#define NW4   147456   // CDIM*CDIM/4
#define NWE   589824   // CDIM*CDIM
#define SCALE2 0.1803368801111244f  // 0.125 * log2(e)

__device__ __forceinline__ unsigned short f2bf(float f) {
  __hip_bfloat16 h = __float2bfloat16(f);  // native cast -> v_cvt_pk_bf16_f32
  return *reinterpret_cast<unsigned short*>(&h);
}

__device__ __forceinline__ void gll16(const void* g, void* l) {
  auto* lp = reinterpret_cast<__attribute__((address_space(3))) unsigned int*>(
      reinterpret_cast<uintptr_t>(l));
  auto* gp = reinterpret_cast<const __attribute__((address_space(1))) unsigned int*>(
      reinterpret_cast<uintptr_t>(g));
  __builtin_amdgcn_global_load_lds(gp, lp, 16, 0, 0);
}

__device__ __forceinline__ f32x4 mfma16(bf16x8 a, bf16x8 b, f32x4 c) {
  return __builtin_amdgcn_mfma_f32_16x16x32_bf16(a, b, c, 0, 0, 0);
}

// Single fused f32->bf16 convert for x, Wq, Wk, Wv, Wp.
__global__ __launch_bounds__(256) void cvt5_kernel(const float* __restrict__ x,
                                                   const float* __restrict__ wq,
                                                   const float* __restrict__ wk,
                                                   const float* __restrict__ wv,
                                                   const float* __restrict__ wp,
                                                   unsigned short* __restrict__ xb,
                                                   unsigned short* __restrict__ wqkb,
                                                   unsigned short* __restrict__ wvb,
                                                   unsigned short* __restrict__ wpb) {
  int gid = blockIdx.x * 256 + threadIdx.x;
  const float* src;
  unsigned short* dst;
  int idx;
  if (gid < NX4) {
    src = x; dst = xb; idx = gid;
  } else {
    int g = gid - NX4;
    int region = g / NW4;
    idx = g - region * NW4;
    if (region == 0)      { src = wq; dst = wqkb; }
    else if (region == 1) { src = wk; dst = wqkb + NWE; }
    else if (region == 2) { src = wv; dst = wvb; }
    else                  { src = wp; dst = wpb; }
  }
  float4 v = reinterpret_cast<const float4*>(src)[idx];
  __hip_bfloat162 lo = __float22bfloat162_rn({v.x, v.y});
  __hip_bfloat162 hi = __float22bfloat162_rn({v.z, v.w});
  uint2 st;
  st.x = *reinterpret_cast<unsigned*>(&lo);
  st.y = *reinterpret_cast<unsigned*>(&hi);
  reinterpret_cast<uint2*>(dst)[idx] = st;
}

// C[m,n] = (sum_k A[m,k]*Bw[n,k] + bias) * colscale.  XOR-swizzled LDS staging.
template <int OUT_BF16, int BIAS_ROW>
__global__ __launch_bounds__(256) void gemm_bt(const unsigned short* __restrict__ A,
                                               const unsigned short* __restrict__ Bw,
                                               const float* __restrict__ bias0,
                                               const float* __restrict__ bias1, int bsplit,
                                               float sc0, float sc1,
                                               void* __restrict__ Cout,
                                               int M, int N, int K) {
  __shared__ char smem[32768];
  const int tid = threadIdx.x;
  const int lane = tid & 63;
  const int w = tid >> 6;
  const int m0 = blockIdx.y * 128, n0 = blockIdx.x * 128;
  const int wr = (w >> 1) * 64, wc = (w & 1) * 64;

  unsigned gaoff[4], gboff[4];
#pragma unroll
  for (int it = 0; it < 4; ++it) {
    int off = it * 4096 + tid * 16;
    int r = off >> 7;
    int cb = (off & 127) ^ ((r & 7) << 4);
    gaoff[it] = (unsigned)((m0 + r) * K * 2 + cb);
    gboff[it] = (unsigned)((n0 + r) * K * 2 + cb);
  }
  const char* Ab = (const char*)A;
  const char* Bb = (const char*)Bw;

  f32x4 acc[4][4] = {};

  for (int ks = 0; ks < K; ks += 64) {
    __syncthreads();
#pragma unroll
    for (int it = 0; it < 4; ++it) {
      gll16(Ab + gaoff[it] + ks * 2, smem + it * 4096 + tid * 16);
      gll16(Bb + gboff[it] + ks * 2, smem + 16384 + it * 4096 + tid * 16);
    }
    __syncthreads();
#pragma unroll
    for (int kk = 0; kk < 2; ++kk) {
      const int cb = kk * 64 + (lane >> 4) * 16;
      bf16x8 av[4], bv[4];
#pragma unroll
      for (int mi = 0; mi < 4; ++mi) {
        int r = wr + mi * 16 + (lane & 15);
        av[mi] = *reinterpret_cast<const bf16x8*>(smem + r * 128 + (cb ^ ((r & 7) << 4)));
      }
#pragma unroll
      for (int ni = 0; ni < 4; ++ni) {
        int r = wc + ni * 16 + (lane & 15);
        bv[ni] = *reinterpret_cast<const bf16x8*>(smem + 16384 + r * 128 + (cb ^ ((r & 7) << 4)));
      }
#pragma unroll
      for (int mi = 0; mi < 4; ++mi)
#pragma unroll
        for (int ni = 0; ni < 4; ++ni)
          acc[mi][ni] = mfma16(av[mi], bv[ni], acc[mi][ni]);
    }
  }

#pragma unroll
  for (int mi = 0; mi < 4; ++mi) {
#pragma unroll
    for (int ni = 0; ni < 4; ++ni) {
      int col = n0 + wc + ni * 16 + (lane & 15);
      float bsc = BIAS_ROW ? 0.f : (col < bsplit ? bias0[col] : bias1[col - bsplit]);
      float scc = BIAS_ROW ? 1.f : (col < bsplit ? sc0 : sc1);
#pragma unroll
      for (int reg = 0; reg < 4; ++reg) {
        int row = m0 + wr + mi * 16 + (lane >> 4) * 4 + reg;
        float v = (acc[mi][ni][reg] + (BIAS_ROW ? bias0[row] : bsc)) * scc;
        if (OUT_BF16)
          ((unsigned short*)Cout)[(size_t)row * N + col] = f2bf(v);
        else
          ((float*)Cout)[(size_t)row * N + col] = v;
      }
    }
  }
}

// LPT order of the 98 useful (qt, subtile) units, descending work.
__device__ const unsigned char qorder[98] = {
    60, 61, 62, 63, 92, 93, 94, 95, 96, 97,           // w=25
    56, 57, 58, 59, 88, 89, 90, 91,                   // w=22
    52, 53, 54, 55, 84, 85, 86, 87,                   // w=19
    48, 49, 50, 51, 80, 81, 82, 83,                   // w=16
    44, 45, 46, 47, 76, 77, 78, 79,                   // w=13
    40, 41, 42, 43, 72, 73, 74, 75,                   // w=10
    28, 29, 30, 31,                                   // w=8
    36, 37, 38, 39, 68, 69, 70, 71, 24, 25, 26, 27,   // w=7
    20, 21, 22, 23,                                   // w=6
    16, 17, 18, 19,                                   // w=5
    32, 33, 34, 35, 64, 65, 66, 67, 12, 13, 14, 15,   // w=4
    8, 9, 10, 11,                                     // w=3
    4, 5, 6, 7,                                       // w=2
    0, 1, 2, 3};                                      // w=1

// Flash attention, instruction-diet edition. 128-thread block = 2 independent
// waves (same rank, 2 consecutive bh); no barriers. Q pre-scaled (log2 domain)
// by the projection GEMM. l-sum folded into the PV MFMA via a ones B-operand.
// 32-bit per-lane offsets precomputed; per-tile uniform part folds to SGPR base.
// qk: [6272][1536] bf16 (q cols 0..767 PRE-SCALED, k cols 768..1535)
// vt: [768][6272] bf16  (row = h*64+d, col = b*1568+j)
// Grid: (24 bh-pairs, 98 rank), 128 threads.
__global__ __launch_bounds__(128) void attn_kernel(const unsigned short* __restrict__ qk,
                                                   const unsigned short* __restrict__ vt,
                                                   unsigned short* __restrict__ yb,
                                                   const int* __restrict__ seg_s,
                                                   const int* __restrict__ seg_e) {
  __shared__ char plds[2][2048];  // per-wave P [16][64] bf16, XOR-swizzled
  const int tid = threadIdx.x;
  const int lane = tid & 63;
  const int w = tid >> 6;
  const int lh = lane & 15, lg = lane >> 4;
  const int bh = blockIdx.x * 2 + w;
  const int b = bh / NHEAD, h = bh % NHEAD;
  const int qsub = qorder[blockIdx.y];
  const int qt = qsub >> 2, wsub = qsub & 3;
  const int rb_q = qt >> 3;   // 0,1,2 = motion blocks; 3 = text tile
  const int qtl = qt & 7;
  char* pw = plds[w];

  // Q fragments (pre-scaled by 0.125*log2e)
  int qr = qt * 64 + wsub * 16 + lh;
  if (qr >= LSEQ) qr = LSEQ - 1;
  const unsigned short* qp = qk + ((size_t)(b * LSEQ + qr) * CQK + h * DHEAD + lg * 8);
  const bf16x8 qf0 = *reinterpret_cast<const bf16x8*>(qp);
  const bf16x8 qf1 = *reinterpret_cast<const bf16x8*>(qp + 32);

  // base pointers (per-b); per-tile uniform offset folds into SGPR base
  const char* qkc = (const char*)qk + (size_t)b * LSEQ * CQK * 2;
  const char* vtc = (const char*)vt + (size_t)b * LSEQ * 2;

  // per-lane 32-bit offsets (loop-invariant)
  unsigned koff[4], voff[4];
#pragma unroll
  for (int nt = 0; nt < 4; ++nt)
    koff[nt] = (unsigned)(((nt * 16 + lh) * CQK + 768 + h * DHEAD + lg * 8) * 2);
#pragma unroll
  for (int dt = 0; dt < 4; ++dt)
    voff[dt] = (unsigned)((h * DHEAD + dt * 16 + lh) * VTN * 2 + lg * 16);

  // loop-invariant mask data
  int f[4], gd[4];
#pragma unroll
  for (int reg = 0; reg < 4; ++reg)
    f[reg] = (qt * 64 + wsub * 16 + lg * 4 + reg) & 511;
#pragma unroll
  for (int nt = 0; nt < 4; ++nt) gd[nt] = qtl * 64 + nt * 16 + lh;

  const int ss = seg_s[b * NSEG + (lh & 7)];
  const int se = seg_e[b * NSEG + (lh & 7)];
  float a_txt[4], a_seg[4];
#pragma unroll
  for (int nt = 0; nt < 4; ++nt) {
    int tc = nt * 16 + lh;
    int j = tc >> 3;
    bool st = (rb_q == 3) || ((rb_q == 1) ? (j != 1) : (j != 0));
    a_txt[nt] = (tc < 32 && st) ? 0.f : -1e30f;
  }
#pragma unroll
  for (int reg = 0; reg < 4; ++reg)
    a_seg[reg] = (rb_q == 3) ? 0.f : ((f[reg] >= ss && f[reg] < se) ? 0.f : -1e30f);

  // P LDS addresses
  int pfa[2];
#pragma unroll
  for (int jc = 0; jc < 2; ++jc)
    pfa[jc] = lh * 128 + (((jc * 32 + lg * 8) * 2) ^ ((lh & 7) << 4));
  int rowoff[4], swzv[4], cbv[4];
#pragma unroll
  for (int reg = 0; reg < 4; ++reg) {
    int row = lg * 4 + reg;
    rowoff[reg] = row * 128;
    swzv[reg] = (row & 7) << 4;
  }
#pragma unroll
  for (int nt = 0; nt < 4; ++nt) cbv[nt] = (nt * 16 + lh) * 2;

  const short oneb = (short)0x3F80;
  const bf16x8 ones = {oneb, oneb, oneb, oneb, oneb, oneb, oneb, oneb};

  f32x4 o[4] = {};
  f32x4 l_acc = {};
  float m_run[4] = {-1e30f, -1e30f, -1e30f, -1e30f};  // log2-domain

  for (int kt = 0; kt < 25; ++kt) {
    bool inc;
    if (rb_q >= 3) inc = true;
    else if (rb_q == 0) inc = (kt <= qtl);
    else inc = (kt == 24) || ((kt & 7) <= qtl);
    if (!inc) continue;

    // K loads (SGPR base + 32-bit voffset)
    const char* kp = qkc + (size_t)kt * (64 * CQK * 2);
    bf16x8 k0[4], k1[4];
#pragma unroll
    for (int nt = 0; nt < 4; ++nt) {
      k0[nt] = *reinterpret_cast<const bf16x8*>(kp + koff[nt]);
      k1[nt] = *reinterpret_cast<const bf16x8*>(kp + koff[nt] + 64);
    }
    // V prefetch (consumed at PV, after softmax VALU)
    const char* vp = vtc + kt * 128;
    bf16x8 vf0[4], vf1[4];
#pragma unroll
    for (int dt = 0; dt < 4; ++dt) {
      vf0[dt] = *reinterpret_cast<const bf16x8*>(vp + voff[dt]);
      vf1[dt] = *reinterpret_cast<const bf16x8*>(vp + voff[dt] + 64);
    }

    // S = Q K^T (already log2-scaled via Q)
    f32x4 s[4];
#pragma unroll
    for (int nt = 0; nt < 4; ++nt) {
      f32x4 z = {};
      z = mfma16(qf0, k0[nt], z);
      z = mfma16(qf1, k1[nt], z);
      s[nt] = z;
    }

    // mask (precomputed adds for the text tile; hoisted compares for diag)
    if (kt == 24) {
#pragma unroll
      for (int nt = 0; nt < 4; ++nt)
#pragma unroll
        for (int reg = 0; reg < 4; ++reg)
          s[nt][reg] += a_txt[nt] + a_seg[reg];
    } else if (rb_q < 3 && (kt & 7) == qtl) {
      const int cbk = kt >> 3;
      const bool strict = (rb_q == 1) ? (cbk != 0) : ((rb_q == 2) ? (cbk == 2) : false);
#pragma unroll
      for (int nt = 0; nt < 4; ++nt)
#pragma unroll
        for (int reg = 0; reg < 4; ++reg) {
          bool ok = strict ? (gd[nt] < f[reg]) : (gd[nt] <= f[reg]);
          s[nt][reg] = ok ? s[nt][reg] : -1e30f;
        }
    }

    // per-row tile max (16-lane reduce)
    float mt[4];
#pragma unroll
    for (int reg = 0; reg < 4; ++reg) {
      float m = fmaxf(fmaxf(fmaxf(s[0][reg], s[1][reg]), s[2][reg]), s[3][reg]);
#pragma unroll
      for (int off = 1; off < 16; off <<= 1) m = fmaxf(m, __shfl_xor(m, off));
      mt[reg] = m;
    }

    // fully-masked tile: nothing to accumulate
    bool allmask = (mt[0] <= -1e29f) & (mt[1] <= -1e29f) & (mt[2] <= -1e29f) & (mt[3] <= -1e29f);
    if (__all(allmask)) continue;

    // defer-max (2^12 headroom in log2 domain)
    bool deferok = (mt[0] <= m_run[0] + 12.f) & (mt[1] <= m_run[1] + 12.f) &
                   (mt[2] <= m_run[2] + 12.f) & (mt[3] <= m_run[3] + 12.f);
    if (!__all(deferok)) {
#pragma unroll
      for (int reg = 0; reg < 4; ++reg) {
        float mn = fmaxf(m_run[reg], mt[reg]);
        float fc = exp2f(m_run[reg] - mn);
        m_run[reg] = mn;
        l_acc[reg] *= fc;
#pragma unroll
        for (int dt = 0; dt < 4; ++dt) o[dt][reg] *= fc;
      }
    }

    // exp + P write (bf16, swizzled) — wave-private LDS, no barrier
#pragma unroll
    for (int reg = 0; reg < 4; ++reg) {
#pragma unroll
      for (int nt = 0; nt < 4; ++nt) {
        float p = exp2f(s[nt][reg] - m_run[reg]);
        *reinterpret_cast<unsigned short*>(pw + rowoff[reg] + (cbv[nt] ^ swzv[reg])) = f2bf(p);
      }
    }

    // O += P @ V ; l += P @ 1 (row-sum rides the matrix pipe)
#pragma unroll
    for (int jc = 0; jc < 2; ++jc) {
      bf16x8 pf = *reinterpret_cast<const bf16x8*>(pw + pfa[jc]);
#pragma unroll
      for (int dt = 0; dt < 4; ++dt)
        o[dt] = mfma16(pf, jc ? vf1[dt] : vf0[dt], o[dt]);
      l_acc = mfma16(pf, ones, l_acc);
    }
  }

  // normalize + write y (bf16)
#pragma unroll
  for (int reg = 0; reg < 4; ++reg) {
    int r = qt * 64 + wsub * 16 + lg * 4 + reg;
    if (r >= LSEQ) continue;
    float inv = 1.0f / l_acc[reg];
#pragma unroll
    for (int dt = 0; dt < 4; ++dt) {
      float v = o[dt][reg] * inv;
      yb[(size_t)(b * LSEQ + r) * CDIM + h * DHEAD + dt * 16 + lh] = f2bf(v);
    }
  }
}

extern "C" void kernel_launch(void* const* d_in, const int* in_sizes, int n_in,
                              void* d_out, int out_size, void* d_ws, size_t ws_size,
                              hipStream_t stream) {
  (void)in_sizes; (void)n_in; (void)out_size;
  const float* x  = (const float*)d_in[0];
  const float* Wq = (const float*)d_in[1];
  const float* bq = (const float*)d_in[2];
  const float* Wk = (const float*)d_in[3];
  const float* bk = (const float*)d_in[4];
  const float* Wv = (const float*)d_in[5];
  const float* bv = (const float*)d_in[6];
  const float* Wp = (const float*)d_in[7];
  const float* bp = (const float*)d_in[8];
  const int* seg_s = (const int*)d_in[9];
  const int* seg_e = (const int*)d_in[10];

  const size_t NX = (size_t)MROWS * CDIM;  // 4,816,896
  const size_t NW = (size_t)CDIM * CDIM;   // 589,824
  const size_t need = (NX * 5 + NW * 4) * 2;
  if (ws_size < need) return;

  unsigned short* xb    = (unsigned short*)d_ws;
  unsigned short* wqkb  = xb + NX;          // [1536][768] (Wq rows, then Wk rows)
  unsigned short* wvb   = wqkb + 2 * NW;
  unsigned short* wpb   = wvb + NW;
  unsigned short* qkbuf = wpb + NW;         // [6272][1536]
  unsigned short* vtbuf = qkbuf + 2 * NX;   // [768][6272]
  unsigned short* ybuf  = vtbuf + NX;       // MUST follow vtbuf (tiny masked OOB reads land here)

  cvt5_kernel<<<(NX4 + 4 * NW4) / 256, 256, 0, stream>>>(x, Wq, Wk, Wv, Wp,
                                                         xb, wqkb, wvb, wpb);

  // Q|K fused projection: [6272][1536]; Q columns pre-scaled into log2 domain
  gemm_bt<1, 0><<<dim3(CQK / 128, MROWS / 128), 256, 0, stream>>>(
      xb, wqkb, bq, bk, 768, SCALE2, 1.0f, qkbuf, MROWS, CQK, CDIM);
  // V^T directly via swapped operands: vt[i][m] = sum_k Wv[i,k] x[m,k] + bv[i]
  gemm_bt<1, 1><<<dim3(MROWS / 128, CDIM / 128), 256, 0, stream>>>(
      wvb, xb, bv, bv, 0, 1.0f, 1.0f, vtbuf, CDIM, MROWS, CDIM);

  attn_kernel<<<dim3(24, 98), 128, 0, stream>>>(qkbuf, vtbuf, ybuf, seg_s, seg_e);

  gemm_bt<0, 0><<<dim3(CDIM / 128, MROWS / 128), 256, 0, stream>>>(
      ybuf, wpb, bp, bp, 1 << 30, 1.0f, 1.0f, d_out, MROWS, CDIM, CDIM);
}

// Round 7
// 159.754 us; speedup vs baseline: 2.0712x; 1.1622x over previous
//
#include <hip/hip_runtime.h>
#include <hip/hip_bf16.h>
#include <stdint.h>

typedef short bf16x8 __attribute__((ext_vector_type(8)));
typedef float f32x4 __attribute__((ext_vector_type(4)));

#define T_M   512
#define ML_   1536
#define LSEQ  1568
#define NHEAD 12
#define DHEAD 64
#define CDIM  768
#define NSEG  8
#define MROWS 6272  // B*L
#define CQK   1536  // q|k concat row stride
#define VTN   6272  // vt row length
#define NX4   1204224  // MROWS*CDIM/4
#define NW4   147456   // CDIM*CDIM/4
#define NWE   589824   // CDIM*CDIM
#define SCALE2 0.1803368801111244f  // 0.125 * log2(e)

__device__ __forceinline__ unsigned short f2bf(float f) {
  __hip_bfloat16 h = __float2bfloat16(f);
  return *reinterpret_cast<unsigned short*>(&h);
}

__device__ __forceinline__ void gll16(const void* g, void* l) {
  auto* lp = reinterpret_cast<__attribute__((address_space(3))) unsigned int*>(
      reinterpret_cast<uintptr_t>(l));
  auto* gp = reinterpret_cast<const __attribute__((address_space(1))) unsigned int*>(
      reinterpret_cast<uintptr_t>(g));
  __builtin_amdgcn_global_load_lds(gp, lp, 16, 0, 0);
}

__device__ __forceinline__ f32x4 mfma16(bf16x8 a, bf16x8 b, f32x4 c) {
  return __builtin_amdgcn_mfma_f32_16x16x32_bf16(a, b, c, 0, 0, 0);
}

// Single fused f32->bf16 convert for x, Wq, Wk, Wv, Wp.
__global__ __launch_bounds__(256) void cvt5_kernel(const float* __restrict__ x,
                                                   const float* __restrict__ wq,
                                                   const float* __restrict__ wk,
                                                   const float* __restrict__ wv,
                                                   const float* __restrict__ wp,
                                                   unsigned short* __restrict__ xb,
                                                   unsigned short* __restrict__ wqkb,
                                                   unsigned short* __restrict__ wvb,
                                                   unsigned short* __restrict__ wpb) {
  int gid = blockIdx.x * 256 + threadIdx.x;
  const float* src;
  unsigned short* dst;
  int idx;
  if (gid < NX4) {
    src = x; dst = xb; idx = gid;
  } else {
    int g = gid - NX4;
    int region = g / NW4;
    idx = g - region * NW4;
    if (region == 0)      { src = wq; dst = wqkb; }
    else if (region == 1) { src = wk; dst = wqkb + NWE; }
    else if (region == 2) { src = wv; dst = wvb; }
    else                  { src = wp; dst = wpb; }
  }
  float4 v = reinterpret_cast<const float4*>(src)[idx];
  __hip_bfloat162 lo = __float22bfloat162_rn({v.x, v.y});
  __hip_bfloat162 hi = __float22bfloat162_rn({v.z, v.w});
  uint2 st;
  st.x = *reinterpret_cast<unsigned*>(&lo);
  st.y = *reinterpret_cast<unsigned*>(&hi);
  reinterpret_cast<uint2*>(dst)[idx] = st;
}

// C[m,n] = (sum_k A[m,k]*Bw[n,k] + bias) * colscale.  XOR-swizzled LDS staging.
template <int OUT_BF16, int BIAS_ROW>
__global__ __launch_bounds__(256) void gemm_bt(const unsigned short* __restrict__ A,
                                               const unsigned short* __restrict__ Bw,
                                               const float* __restrict__ bias0,
                                               const float* __restrict__ bias1, int bsplit,
                                               float sc0, float sc1,
                                               void* __restrict__ Cout,
                                               int M, int N, int K) {
  __shared__ char smem[32768];
  const int tid = threadIdx.x;
  const int lane = tid & 63;
  const int w = tid >> 6;
  const int m0 = blockIdx.y * 128, n0 = blockIdx.x * 128;
  const int wr = (w >> 1) * 64, wc = (w & 1) * 64;

  unsigned gaoff[4], gboff[4];
#pragma unroll
  for (int it = 0; it < 4; ++it) {
    int off = it * 4096 + tid * 16;
    int r = off >> 7;
    int cb = (off & 127) ^ ((r & 7) << 4);
    gaoff[it] = (unsigned)((m0 + r) * K * 2 + cb);
    gboff[it] = (unsigned)((n0 + r) * K * 2 + cb);
  }
  const char* Ab = (const char*)A;
  const char* Bb = (const char*)Bw;

  f32x4 acc[4][4] = {};

  for (int ks = 0; ks < K; ks += 64) {
    __syncthreads();
#pragma unroll
    for (int it = 0; it < 4; ++it) {
      gll16(Ab + gaoff[it] + ks * 2, smem + it * 4096 + tid * 16);
      gll16(Bb + gboff[it] + ks * 2, smem + 16384 + it * 4096 + tid * 16);
    }
    __syncthreads();
#pragma unroll
    for (int kk = 0; kk < 2; ++kk) {
      const int cb = kk * 64 + (lane >> 4) * 16;
      bf16x8 av[4], bv[4];
#pragma unroll
      for (int mi = 0; mi < 4; ++mi) {
        int r = wr + mi * 16 + (lane & 15);
        av[mi] = *reinterpret_cast<const bf16x8*>(smem + r * 128 + (cb ^ ((r & 7) << 4)));
      }
#pragma unroll
      for (int ni = 0; ni < 4; ++ni) {
        int r = wc + ni * 16 + (lane & 15);
        bv[ni] = *reinterpret_cast<const bf16x8*>(smem + 16384 + r * 128 + (cb ^ ((r & 7) << 4)));
      }
#pragma unroll
      for (int mi = 0; mi < 4; ++mi)
#pragma unroll
        for (int ni = 0; ni < 4; ++ni)
          acc[mi][ni] = mfma16(av[mi], bv[ni], acc[mi][ni]);
    }
  }

#pragma unroll
  for (int mi = 0; mi < 4; ++mi) {
#pragma unroll
    for (int ni = 0; ni < 4; ++ni) {
      int col = n0 + wc + ni * 16 + (lane & 15);
      float bsc = BIAS_ROW ? 0.f : (col < bsplit ? bias0[col] : bias1[col - bsplit]);
      float scc = BIAS_ROW ? 1.f : (col < bsplit ? sc0 : sc1);
#pragma unroll
      for (int reg = 0; reg < 4; ++reg) {
        int row = m0 + wr + mi * 16 + (lane >> 4) * 4 + reg;
        float v = (acc[mi][ni][reg] + (BIAS_ROW ? bias0[row] : bsc)) * scc;
        if (OUT_BF16)
          ((unsigned short*)Cout)[(size_t)row * N + col] = f2bf(v);
        else
          ((float*)Cout)[(size_t)row * N + col] = v;
      }
    }
  }
}

// LPT order of the 13 qt-groups (12 qt-pairs + text), by union tile count:
// cnt: g0..3: 2,4,6,8; g4..7: 7,13,19,25; g8..11: 7,13,19,25; g12: 25
__device__ const unsigned char gorder[13] = {7, 11, 12, 6, 10, 5, 9, 3, 4, 8, 2, 1, 0};

// Flash attention with block-level K/V sharing in LDS.
// Block = 512 threads = 8 waves, covering 128 q-rows (qt pair 2g, 2g+1) of one
// (b,h). Per KV tile: K (64x128B) + V^T (64x128B) staged once into LDS via
// global_load_lds (inverse-swizzled source), double-buffered; all 8 waves read
// fragments via swizzled ds_read_b128. One barrier per tile. 8x less cache
// traffic than per-wave global reads. Waves 0-3 stage K, 4-7 stage V.
// qk: [6272][1536] bf16 (q cols 0..767 PRE-SCALED by 0.125*log2e, k 768..1535)
// vt: [768][6272] bf16  (row = h*64+d, col = b*1568+j)
// Grid: (48 bh, 13 group), 512 threads.
__global__ __launch_bounds__(512) void attn_kernel(const unsigned short* __restrict__ qk,
                                                   const unsigned short* __restrict__ vt,
                                                   unsigned short* __restrict__ yb,
                                                   const int* __restrict__ seg_s,
                                                   const int* __restrict__ seg_e) {
  __shared__ char smem[49152];  // [2][K 8KB | V 8KB] dbuf, then P[8][2048]
  const int tid = threadIdx.x;
  const int lane = tid & 63;
  const int w = tid >> 6;
  const int lh = lane & 15, lg = lane >> 4;
  const int bh = blockIdx.x;
  const int b = bh / NHEAD, h = bh % NHEAD;
  const int g = gorder[blockIdx.y];
  const int qt = (g == 12) ? 24 : (2 * g + (w >> 2));
  const int wsub = (g == 12) ? (w & 1) : (w & 3);
  const int rb_q = qt >> 3;
  const int qtl = qt & 7;
  // block-uniform union iteration params (uses the odd/larger qt of the pair)
  const int urb = (g >= 12) ? 3 : (g >> 2);
  const int uqtl = (2 * g + 1) & 7;
  const int cnt = (urb == 0) ? (uqtl + 1) : (urb < 3 ? 3 * (uqtl + 1) + 1 : 25);
  char* pw = smem + 32768 + w * 2048;

  // Q fragments (pre-scaled into log2 domain)
  int qr = qt * 64 + wsub * 16 + lh;
  if (qr >= LSEQ) qr = LSEQ - 1;
  const unsigned short* qp = qk + ((size_t)(b * LSEQ + qr) * CQK + h * DHEAD + lg * 8);
  const bf16x8 qf0 = *reinterpret_cast<const bf16x8*>(qp);
  const bf16x8 qf1 = *reinterpret_cast<const bf16x8*>(qp + 32);

  const char* qkc = (const char*)qk + (size_t)b * LSEQ * CQK * 2;
  const char* vtc = (const char*)vt + (size_t)b * LSEQ * 2;

  // ---- staging precompute (waves 0-3: K rows, waves 4-7: V rows) ----
  const int cbyte = (((lane & 7) ^ (lane >> 3)) << 4);  // inverse-swizzle src col
  const int rlA = (w & 3) * 16 + (lane >> 3);           // + t*8 -> local row
  const char* kqbase = qkc + (768 + h * DHEAD) * 2 + cbyte;  // + gr*3072
  size_t vbo[2];
#pragma unroll
  for (int t = 0; t < 2; ++t)
    vbo[t] = (size_t)(h * DHEAD + rlA + t * 8) * (VTN * 2) + cbyte;  // + kt*128

  // ---- fragment-read precompute ----
  const int c0 = (lg * 16) ^ ((lh & 7) << 4);  // swizzled col base; ^64 for hi half

  // loop-invariant mask data
  int f[4], gd[4];
#pragma unroll
  for (int reg = 0; reg < 4; ++reg)
    f[reg] = (qt * 64 + wsub * 16 + lg * 4 + reg) & 511;
#pragma unroll
  for (int nt = 0; nt < 4; ++nt) gd[nt] = qtl * 64 + nt * 16 + lh;

  const int ss = seg_s[b * NSEG + (lh & 7)];
  const int se = seg_e[b * NSEG + (lh & 7)];
  float a_txt[4], a_seg[4];
#pragma unroll
  for (int nt = 0; nt < 4; ++nt) {
    int tc = nt * 16 + lh;
    int j = tc >> 3;
    bool st = (rb_q == 3) || ((rb_q == 1) ? (j != 1) : (j != 0));
    a_txt[nt] = (tc < 32 && st) ? 0.f : -1e30f;
  }
#pragma unroll
  for (int reg = 0; reg < 4; ++reg)
    a_seg[reg] = (rb_q == 3) ? 0.f : ((f[reg] >= ss && f[reg] < se) ? 0.f : -1e30f);

  // P LDS addresses
  int pfa[2];
#pragma unroll
  for (int jc = 0; jc < 2; ++jc)
    pfa[jc] = lh * 128 + (((jc * 32 + lg * 8) * 2) ^ ((lh & 7) << 4));
  int rowoff[4], swzv[4], cbv[4];
#pragma unroll
  for (int reg = 0; reg < 4; ++reg) {
    int row = lg * 4 + reg;
    rowoff[reg] = row * 128;
    swzv[reg] = (row & 7) << 4;
  }
#pragma unroll
  for (int nt = 0; nt < 4; ++nt) cbv[nt] = (nt * 16 + lh) * 2;

  const short oneb = (short)0x3F80;
  const bf16x8 ones = {oneb, oneb, oneb, oneb, oneb, oneb, oneb, oneb};

  f32x4 o[4] = {};
  f32x4 l_acc = {};
  float m_run[4] = {-1e30f, -1e30f, -1e30f, -1e30f};

  // ---- prologue: stage tile kt=0 into buf 0 ----
#pragma unroll
  for (int t = 0; t < 2; ++t) {
    char* dst = smem + (2 * w + t) * 1024 + lane * 16;
    const char* src;
    if (w < 4) {
      int gr = rlA + t * 8;  // kt=0
      src = kqbase + (size_t)gr * (CQK * 2);
    } else {
      src = vtc + vbo[t];
    }
    gll16(src, dst);
  }
  __syncthreads();

  int kt = 0, cur = 0;
  for (int i = 0; i < cnt; ++i) {
    int nkt;
    if (urb == 0 || urb == 3) nkt = kt + 1;
    else nkt = ((kt & 7) < uqtl) ? kt + 1 : (kt & ~7) + 8;
    if (nkt > 24) nkt = 24;

    // stage next tile into the other buffer (block-uniform)
    if (i + 1 < cnt) {
#pragma unroll
      for (int t = 0; t < 2; ++t) {
        char* dst = smem + (cur ^ 1) * 16384 + (2 * w + t) * 1024 + lane * 16;
        const char* src;
        if (w < 4) {
          int gr = nkt * 64 + rlA + t * 8;
          if (gr > LSEQ - 1) gr = LSEQ - 1;
          src = kqbase + (size_t)gr * (CQK * 2);
        } else {
          src = vtc + vbo[t] + (size_t)nkt * 128;
        }
        gll16(src, dst);
      }
    }

    // wave-level skip: even-qt waves exclude the pair-partner's diagonal tile
    const bool wave_skip = (rb_q < 3) && (kt < 24) && ((kt & 7) == qtl + 1);
    if (!wave_skip) {
      const char* kb = smem + cur * 16384;
      const char* vb = kb + 8192;

      // S = Q K^T from LDS
      f32x4 s[4];
#pragma unroll
      for (int nt = 0; nt < 4; ++nt) {
        const char* kr = kb + (nt * 16 + lh) * 128;
        bf16x8 k0 = *reinterpret_cast<const bf16x8*>(kr + c0);
        bf16x8 k1 = *reinterpret_cast<const bf16x8*>(kr + (c0 ^ 64));
        f32x4 z = {};
        z = mfma16(qf0, k0, z);
        z = mfma16(qf1, k1, z);
        s[nt] = z;
      }

      // mask
      if (kt == 24) {
#pragma unroll
        for (int nt = 0; nt < 4; ++nt)
#pragma unroll
          for (int reg = 0; reg < 4; ++reg)
            s[nt][reg] += a_txt[nt] + a_seg[reg];
      } else if (rb_q < 3 && (kt & 7) == qtl) {
        const int cbk = kt >> 3;
        const bool strict = (rb_q == 1) ? (cbk != 0) : ((rb_q == 2) ? (cbk == 2) : false);
#pragma unroll
        for (int nt = 0; nt < 4; ++nt)
#pragma unroll
          for (int reg = 0; reg < 4; ++reg) {
            bool ok = strict ? (gd[nt] < f[reg]) : (gd[nt] <= f[reg]);
            s[nt][reg] = ok ? s[nt][reg] : -1e30f;
          }
      }

      // per-row tile max (16-lane reduce)
      float mt[4];
#pragma unroll
      for (int reg = 0; reg < 4; ++reg) {
        float m = fmaxf(fmaxf(fmaxf(s[0][reg], s[1][reg]), s[2][reg]), s[3][reg]);
#pragma unroll
        for (int off = 1; off < 16; off <<= 1) m = fmaxf(m, __shfl_xor(m, off));
        mt[reg] = m;
      }

      bool allmask = (mt[0] <= -1e29f) & (mt[1] <= -1e29f) &
                     (mt[2] <= -1e29f) & (mt[3] <= -1e29f);
      if (!__all(allmask)) {
        bool deferok = (mt[0] <= m_run[0] + 12.f) & (mt[1] <= m_run[1] + 12.f) &
                       (mt[2] <= m_run[2] + 12.f) & (mt[3] <= m_run[3] + 12.f);
        if (!__all(deferok)) {
#pragma unroll
          for (int reg = 0; reg < 4; ++reg) {
            float mn = fmaxf(m_run[reg], mt[reg]);
            float fc = exp2f(m_run[reg] - mn);
            m_run[reg] = mn;
            l_acc[reg] *= fc;
#pragma unroll
            for (int dt = 0; dt < 4; ++dt) o[dt][reg] *= fc;
          }
        }

        // exp + P write (bf16, swizzled) — wave-private region
#pragma unroll
        for (int reg = 0; reg < 4; ++reg) {
#pragma unroll
          for (int nt = 0; nt < 4; ++nt) {
            float p = exp2f(s[nt][reg] - m_run[reg]);
            *reinterpret_cast<unsigned short*>(pw + rowoff[reg] + (cbv[nt] ^ swzv[reg])) =
                f2bf(p);
          }
        }

        // O += P @ V ; l += P @ 1
#pragma unroll
        for (int jc = 0; jc < 2; ++jc) {
          bf16x8 pf = *reinterpret_cast<const bf16x8*>(pw + pfa[jc]);
#pragma unroll
          for (int dt = 0; dt < 4; ++dt) {
            bf16x8 vf = *reinterpret_cast<const bf16x8*>(
                vb + (dt * 16 + lh) * 128 + (c0 ^ (jc << 6)));
            o[dt] = mfma16(pf, vf, o[dt]);
          }
          l_acc = mfma16(pf, ones, l_acc);
        }
      }
    }

    __syncthreads();  // staged next buf complete + everyone done with cur
    cur ^= 1;
    kt = nkt;
  }

  // normalize + write y (text group: only waves 0,1 store, rest are duplicates)
  if (g != 12 || w < 2) {
#pragma unroll
    for (int reg = 0; reg < 4; ++reg) {
      int r = qt * 64 + wsub * 16 + lg * 4 + reg;
      if (r >= LSEQ) continue;
      float inv = 1.0f / l_acc[reg];
#pragma unroll
      for (int dt = 0; dt < 4; ++dt) {
        float v = o[dt][reg] * inv;
        yb[(size_t)(b * LSEQ + r) * CDIM + h * DHEAD + dt * 16 + lh] = f2bf(v);
      }
    }
  }
}

extern "C" void kernel_launch(void* const* d_in, const int* in_sizes, int n_in,
                              void* d_out, int out_size, void* d_ws, size_t ws_size,
                              hipStream_t stream) {
  (void)in_sizes; (void)n_in; (void)out_size;
  const float* x  = (const float*)d_in[0];
  const float* Wq = (const float*)d_in[1];
  const float* bq = (const float*)d_in[2];
  const float* Wk = (const float*)d_in[3];
  const float* bk = (const float*)d_in[4];
  const float* Wv = (const float*)d_in[5];
  const float* bv = (const float*)d_in[6];
  const float* Wp = (const float*)d_in[7];
  const float* bp = (const float*)d_in[8];
  const int* seg_s = (const int*)d_in[9];
  const int* seg_e = (const int*)d_in[10];

  const size_t NX = (size_t)MROWS * CDIM;  // 4,816,896
  const size_t NW = (size_t)CDIM * CDIM;   // 589,824
  const size_t need = (NX * 5 + NW * 4) * 2;
  if (ws_size < need) return;

  unsigned short* xb    = (unsigned short*)d_ws;
  unsigned short* wqkb  = xb + NX;          // [1536][768] (Wq rows, then Wk rows)
  unsigned short* wvb   = wqkb + 2 * NW;
  unsigned short* wpb   = wvb + NW;
  unsigned short* qkbuf = wpb + NW;         // [6272][1536]
  unsigned short* vtbuf = qkbuf + 2 * NX;   // [768][6272]
  unsigned short* ybuf  = vtbuf + NX;       // MUST follow vtbuf (tiny masked OOB reads land here)

  cvt5_kernel<<<(NX4 + 4 * NW4) / 256, 256, 0, stream>>>(x, Wq, Wk, Wv, Wp,
                                                         xb, wqkb, wvb, wpb);

  // Q|K fused projection: [6272][1536]; Q columns pre-scaled into log2 domain
  gemm_bt<1, 0><<<dim3(CQK / 128, MROWS / 128), 256, 0, stream>>>(
      xb, wqkb, bq, bk, 768, SCALE2, 1.0f, qkbuf, MROWS, CQK, CDIM);
  // V^T directly via swapped operands: vt[i][m] = sum_k Wv[i,k] x[m,k] + bv[i]
  gemm_bt<1, 1><<<dim3(MROWS / 128, CDIM / 128), 256, 0, stream>>>(
      wvb, xb, bv, bv, 0, 1.0f, 1.0f, vtbuf, CDIM, MROWS, CDIM);

  attn_kernel<<<dim3(48, 13), 512, 0, stream>>>(qkbuf, vtbuf, ybuf, seg_s, seg_e);

  gemm_bt<0, 0><<<dim3(CDIM / 128, MROWS / 128), 256, 0, stream>>>(
      ybuf, wpb, bp, bp, 1 << 30, 1.0f, 1.0f, d_out, MROWS, CDIM, CDIM);
}

// Round 8
// 127.151 us; speedup vs baseline: 2.6023x; 1.2564x over previous
//
#include <hip/hip_runtime.h>
#include <hip/hip_bf16.h>
#include <stdint.h>

typedef short bf16x8 __attribute__((ext_vector_type(8)));
typedef float f32x4 __attribute__((ext_vector_type(4)));

#define T_M   512
#define ML_   1536
#define LSEQ  1568
#define NHEAD 12
#define DHEAD 64
#define CDIM  768
#define NSEG  8
#define MROWS 6272  // B*L
#define CQK   1536  // q|k concat row stride
#define VTN   6272  // vt row length
#define NX4   1204224  // MROWS*CDIM/4
#define NW4   147456   // CDIM*CDIM/4
#define NWE   589824   // CDIM*CDIM
#define SCALE2 0.1803368801111244f  // 0.125 * log2(e)

__device__ __forceinline__ unsigned short f2bf(float f) {
  __hip_bfloat16 h = __float2bfloat16(f);
  return *reinterpret_cast<unsigned short*>(&h);
}

__device__ __forceinline__ void gll16(const void* g, void* l) {
  auto* lp = reinterpret_cast<__attribute__((address_space(3))) unsigned int*>(
      reinterpret_cast<uintptr_t>(l));
  auto* gp = reinterpret_cast<const __attribute__((address_space(1))) unsigned int*>(
      reinterpret_cast<uintptr_t>(g));
  __builtin_amdgcn_global_load_lds(gp, lp, 16, 0, 0);
}

__device__ __forceinline__ f32x4 mfma16(bf16x8 a, bf16x8 b, f32x4 c) {
  return __builtin_amdgcn_mfma_f32_16x16x32_bf16(a, b, c, 0, 0, 0);
}

// Single fused f32->bf16 convert for x, Wq, Wk, Wv, Wp.
__global__ __launch_bounds__(256) void cvt5_kernel(const float* __restrict__ x,
                                                   const float* __restrict__ wq,
                                                   const float* __restrict__ wk,
                                                   const float* __restrict__ wv,
                                                   const float* __restrict__ wp,
                                                   unsigned short* __restrict__ xb,
                                                   unsigned short* __restrict__ wqkb,
                                                   unsigned short* __restrict__ wvb,
                                                   unsigned short* __restrict__ wpb) {
  int gid = blockIdx.x * 256 + threadIdx.x;
  const float* src;
  unsigned short* dst;
  int idx;
  if (gid < NX4) {
    src = x; dst = xb; idx = gid;
  } else {
    int g = gid - NX4;
    int region = g / NW4;
    idx = g - region * NW4;
    if (region == 0)      { src = wq; dst = wqkb; }
    else if (region == 1) { src = wk; dst = wqkb + NWE; }
    else if (region == 2) { src = wv; dst = wvb; }
    else                  { src = wp; dst = wpb; }
  }
  float4 v = reinterpret_cast<const float4*>(src)[idx];
  __hip_bfloat162 lo = __float22bfloat162_rn({v.x, v.y});
  __hip_bfloat162 hi = __float22bfloat162_rn({v.z, v.w});
  uint2 st;
  st.x = *reinterpret_cast<unsigned*>(&lo);
  st.y = *reinterpret_cast<unsigned*>(&hi);
  reinterpret_cast<uint2*>(dst)[idx] = st;
}

// Shared GEMM body: C[m,n] = (sum_k A[m,k]*Bw[n,k] + bias) * colscale.
// BM=BN=128, BK=64; 4 waves (2x2). XOR-swizzled LDS staging.
template <int OUT_BF16, int BIAS_ROW>
__device__ __forceinline__ void gemm_body(char* smem, int bx, int by,
                                          const unsigned short* __restrict__ A,
                                          const unsigned short* __restrict__ Bw,
                                          const float* __restrict__ bias0,
                                          const float* __restrict__ bias1, int bsplit,
                                          float sc0, float sc1,
                                          void* __restrict__ Cout,
                                          int M, int N, int K) {
  const int tid = threadIdx.x;
  const int lane = tid & 63;
  const int w = tid >> 6;
  const int m0 = by * 128, n0 = bx * 128;
  const int wr = (w >> 1) * 64, wc = (w & 1) * 64;

  unsigned gaoff[4], gboff[4];
#pragma unroll
  for (int it = 0; it < 4; ++it) {
    int off = it * 4096 + tid * 16;
    int r = off >> 7;
    int cb = (off & 127) ^ ((r & 7) << 4);
    gaoff[it] = (unsigned)((m0 + r) * K * 2 + cb);
    gboff[it] = (unsigned)((n0 + r) * K * 2 + cb);
  }
  const char* Ab = (const char*)A;
  const char* Bb = (const char*)Bw;

  f32x4 acc[4][4] = {};

  for (int ks = 0; ks < K; ks += 64) {
    __syncthreads();
#pragma unroll
    for (int it = 0; it < 4; ++it) {
      gll16(Ab + gaoff[it] + ks * 2, smem + it * 4096 + tid * 16);
      gll16(Bb + gboff[it] + ks * 2, smem + 16384 + it * 4096 + tid * 16);
    }
    __syncthreads();
#pragma unroll
    for (int kk = 0; kk < 2; ++kk) {
      const int cb = kk * 64 + (lane >> 4) * 16;
      bf16x8 av[4], bv[4];
#pragma unroll
      for (int mi = 0; mi < 4; ++mi) {
        int r = wr + mi * 16 + (lane & 15);
        av[mi] = *reinterpret_cast<const bf16x8*>(smem + r * 128 + (cb ^ ((r & 7) << 4)));
      }
#pragma unroll
      for (int ni = 0; ni < 4; ++ni) {
        int r = wc + ni * 16 + (lane & 15);
        bv[ni] = *reinterpret_cast<const bf16x8*>(smem + 16384 + r * 128 + (cb ^ ((r & 7) << 4)));
      }
#pragma unroll
      for (int mi = 0; mi < 4; ++mi)
#pragma unroll
        for (int ni = 0; ni < 4; ++ni)
          acc[mi][ni] = mfma16(av[mi], bv[ni], acc[mi][ni]);
    }
  }

#pragma unroll
  for (int mi = 0; mi < 4; ++mi) {
#pragma unroll
    for (int ni = 0; ni < 4; ++ni) {
      int col = n0 + wc + ni * 16 + (lane & 15);
      float bsc = BIAS_ROW ? 0.f : (col < bsplit ? bias0[col] : bias1[col - bsplit]);
      float scc = BIAS_ROW ? 1.f : (col < bsplit ? sc0 : sc1);
#pragma unroll
      for (int reg = 0; reg < 4; ++reg) {
        int row = m0 + wr + mi * 16 + (lane >> 4) * 4 + reg;
        float v = (acc[mi][ni][reg] + (BIAS_ROW ? bias0[row] : bsc)) * scc;
        if (OUT_BF16)
          ((unsigned short*)Cout)[(size_t)row * N + col] = f2bf(v);
        else
          ((float*)Cout)[(size_t)row * N + col] = v;
      }
    }
  }
}

// Fused pre-attention GEMMs: blocks [0,588) = Q|K projection (12x49 tiles),
// blocks [588,882) = V^T projection (49x6 tiles). One launch -> better fill.
__global__ __launch_bounds__(256) void gemm_pre(const unsigned short* __restrict__ xb,
                                                const unsigned short* __restrict__ wqkb,
                                                const unsigned short* __restrict__ wvb,
                                                const float* __restrict__ bq,
                                                const float* __restrict__ bk,
                                                const float* __restrict__ bv,
                                                unsigned short* __restrict__ qkbuf,
                                                unsigned short* __restrict__ vtbuf) {
  __shared__ char smem[32768];
  int bid = blockIdx.x;
  if (bid < 588) {
    gemm_body<1, 0>(smem, bid % 12, bid / 12, xb, wqkb, bq, bk, 768, SCALE2, 1.0f,
                    qkbuf, MROWS, CQK, CDIM);
  } else {
    int b2 = bid - 588;
    gemm_body<1, 1>(smem, b2 % 49, b2 / 49, wvb, xb, bv, bv, 0, 1.0f, 1.0f,
                    vtbuf, CDIM, MROWS, CDIM);
  }
}

// Final projection GEMM (separate: depends on attn output).
__global__ __launch_bounds__(256) void gemm_post(const unsigned short* __restrict__ ybuf,
                                                 const unsigned short* __restrict__ wpb,
                                                 const float* __restrict__ bp,
                                                 float* __restrict__ out) {
  __shared__ char smem[32768];
  gemm_body<0, 0>(smem, blockIdx.x, blockIdx.y, ybuf, wpb, bp, bp, 1 << 30, 1.0f, 1.0f,
                  out, MROWS, CDIM, CDIM);
}

// LPT order of the 13 qt-groups (12 qt-pairs + text), by union tile count.
__device__ const unsigned char gorder[13] = {7, 11, 12, 6, 10, 5, 9, 3, 4, 8, 2, 1, 0};

// Flash attention, LDS K/V sharing + SWAPPED QK^T (lane-local softmax).
// Block = 512 threads = 8 waves, 128 q-rows (qt pair) of one (b,h).
// Per KV tile: K + V^T staged once via global_load_lds (dbuf); all waves read
// swizzled ds_read_b128 fragments. mfma(K,Q) puts a full q-row's S in-lane:
// row-max = 15 fmax + 2 shfl; P-write = 4 packed ds_write_b64; defer-max.
// qk: [6272][1536] bf16 (q cols 0..767 PRE-SCALED by 0.125*log2e, k 768..1535)
// vt: [768][6272] bf16  (row = h*64+d, col = b*1568+j)
// Grid: (48 bh, 13 group), 512 threads.
__global__ __launch_bounds__(512) void attn_kernel(const unsigned short* __restrict__ qk,
                                                   const unsigned short* __restrict__ vt,
                                                   unsigned short* __restrict__ yb,
                                                   const int* __restrict__ seg_s,
                                                   const int* __restrict__ seg_e) {
  __shared__ char smem[49152];  // [2][K 8KB | V 8KB] dbuf, then P[8][2048]
  const int tid = threadIdx.x;
  const int lane = tid & 63;
  const int w = tid >> 6;
  const int lh = lane & 15, lg = lane >> 4;
  const int bh = blockIdx.x;
  const int b = bh / NHEAD, h = bh % NHEAD;
  const int g = gorder[blockIdx.y];
  const int qt = (g == 12) ? 24 : (2 * g + (w >> 2));
  const int wsub = (g == 12) ? (w & 1) : (w & 3);
  const int rb_q = qt >> 3;
  const int qtl = qt & 7;
  const int urb = (g >= 12) ? 3 : (g >> 2);
  const int uqtl = (2 * g + 1) & 7;
  const int cnt = (urb == 0) ? (uqtl + 1) : (urb < 3 ? 3 * (uqtl + 1) + 1 : 25);
  char* pw = smem + 32768 + w * 2048;

  // Q fragments (pre-scaled into log2 domain); used as the MFMA B-operand.
  int qr = qt * 64 + wsub * 16 + lh;
  if (qr >= LSEQ) qr = LSEQ - 1;
  const unsigned short* qp = qk + ((size_t)(b * LSEQ + qr) * CQK + h * DHEAD + lg * 8);
  const bf16x8 qf0 = *reinterpret_cast<const bf16x8*>(qp);
  const bf16x8 qf1 = *reinterpret_cast<const bf16x8*>(qp + 32);

  const char* qkc = (const char*)qk + (size_t)b * LSEQ * CQK * 2;
  const char* vtc = (const char*)vt + (size_t)b * LSEQ * 2;

  // ---- staging precompute (waves 0-3: K rows, waves 4-7: V rows) ----
  const int cbyte = (((lane & 7) ^ (lane >> 3)) << 4);
  const int rlA = (w & 3) * 16 + (lane >> 3);
  const char* kqbase = qkc + (768 + h * DHEAD) * 2 + cbyte;
  size_t vbo[2];
#pragma unroll
  for (int t = 0; t < 2; ++t)
    vbo[t] = (size_t)(h * DHEAD + rlA + t * 8) * (VTN * 2) + cbyte;

  // ---- fragment-read precompute ----
  const int c0 = (lg * 16) ^ ((lh & 7) << 4);

  // loop-invariant mask data (swapped layout: lane q = lh; k = nt*16+lg*4+reg)
  const int f_lane = (qt * 64 + wsub * 16 + lh) & 511;  // q frame per lane
  float a_k[4];   // text-tile k-col mask (validity + stream), per nt
#pragma unroll
  for (int nt = 0; nt < 4; ++nt) {
    int j = nt * 2 + (lg >> 1);
    bool st = (rb_q == 3) || ((rb_q == 1) ? (j != 1) : (j != 0));
    a_k[nt] = (nt < 2 && st) ? 0.f : -1e30f;
  }
  float w4[4];    // text-tile segment window (q frame in segment ii), per reg
#pragma unroll
  for (int reg = 0; reg < 4; ++reg) {
    int ii = (lg * 4 + reg) & 7;
    int ssv = seg_s[b * NSEG + ii], sev = seg_e[b * NSEG + ii];
    w4[reg] = (rb_q == 3) ? 0.f : ((f_lane >= ssv && f_lane < sev) ? 0.f : -1e30f);
  }

  // P LDS addresses
  int pfa[2];
#pragma unroll
  for (int jc = 0; jc < 2; ++jc)
    pfa[jc] = lh * 128 + (((jc * 32 + lg * 8) * 2) ^ ((lh & 7) << 4));
  int pwr[4];  // packed P-write addrs, per nt (8B each)
#pragma unroll
  for (int nt = 0; nt < 4; ++nt)
    pwr[nt] = lh * 128 + ((nt * 32 + lg * 8) ^ ((lh & 7) << 4));

  const short oneb = (short)0x3F80;
  const bf16x8 ones = {oneb, oneb, oneb, oneb, oneb, oneb, oneb, oneb};

  f32x4 o[4] = {};
  f32x4 l_acc = {};
  float m_run = -1e30f;  // per-lane (q = lh), log2 domain

  // ---- prologue: stage tile kt=0 into buf 0 ----
#pragma unroll
  for (int t = 0; t < 2; ++t) {
    char* dst = smem + (2 * w + t) * 1024 + lane * 16;
    const char* src;
    if (w < 4) {
      src = kqbase + (size_t)(rlA + t * 8) * (CQK * 2);
    } else {
      src = vtc + vbo[t];
    }
    gll16(src, dst);
  }
  __syncthreads();

  int kt = 0, cur = 0;
  for (int i = 0; i < cnt; ++i) {
    int nkt;
    if (urb == 0 || urb == 3) nkt = kt + 1;
    else nkt = ((kt & 7) < uqtl) ? kt + 1 : (kt & ~7) + 8;
    if (nkt > 24) nkt = 24;

    // stage next tile into the other buffer (block-uniform)
    if (i + 1 < cnt) {
#pragma unroll
      for (int t = 0; t < 2; ++t) {
        char* dst = smem + (cur ^ 1) * 16384 + (2 * w + t) * 1024 + lane * 16;
        const char* src;
        if (w < 4) {
          int gr = nkt * 64 + rlA + t * 8;
          if (gr > LSEQ - 1) gr = LSEQ - 1;
          src = kqbase + (size_t)gr * (CQK * 2);
        } else {
          src = vtc + vbo[t] + (size_t)nkt * 128;
        }
        gll16(src, dst);
      }
    }

    const bool wave_skip = (rb_q < 3) && (kt < 24) && ((kt & 7) == qtl + 1);
    if (!wave_skip) {
      const char* kb = smem + cur * 16384;
      const char* vb = kb + 8192;

      // S^T = K Q^T from LDS (swapped operands: A=K, B=Q)
      // s[nt][reg] = S[q=lh][k = nt*16 + lg*4 + reg]
      f32x4 s[4];
#pragma unroll
      for (int nt = 0; nt < 4; ++nt) {
        const char* kr = kb + (nt * 16 + lh) * 128;
        bf16x8 k0 = *reinterpret_cast<const bf16x8*>(kr + c0);
        bf16x8 k1 = *reinterpret_cast<const bf16x8*>(kr + (c0 ^ 64));
        f32x4 z = {};
        z = mfma16(k0, qf0, z);
        z = mfma16(k1, qf1, z);
        s[nt] = z;
      }

      // mask
      if (kt == 24) {
#pragma unroll
        for (int nt = 0; nt < 4; ++nt)
#pragma unroll
          for (int reg = 0; reg < 4; ++reg)
            s[nt][reg] += a_k[nt] + w4[reg];
      } else if (rb_q < 3 && (kt & 7) == qtl) {
        const int cbk = kt >> 3;
        const bool strict = (rb_q == 1) ? (cbk != 0) : ((rb_q == 2) ? (cbk == 2) : false);
        const int dbase = qtl * 64 + lg * 4;
#pragma unroll
        for (int nt = 0; nt < 4; ++nt)
#pragma unroll
          for (int reg = 0; reg < 4; ++reg) {
            int kcol = dbase + nt * 16 + reg;
            bool ok = strict ? (kcol < f_lane) : (kcol <= f_lane);
            s[nt][reg] = ok ? s[nt][reg] : -1e30f;
          }
      }

      // lane-local row max (15 fmax) + 2 cross-lg shfl steps
      float mt = s[0][0];
#pragma unroll
      for (int nt = 0; nt < 4; ++nt)
#pragma unroll
        for (int reg = 0; reg < 4; ++reg)
          if (nt || reg) mt = fmaxf(mt, s[nt][reg]);
      mt = fmaxf(mt, __shfl_xor(mt, 16));
      mt = fmaxf(mt, __shfl_xor(mt, 32));

      if (!__all(mt <= -1e29f)) {
        // defer-max (2^12 headroom)
        if (!__all(mt <= m_run + 12.f)) {
          float mold = m_run;
          m_run = fmaxf(m_run, mt);
          float fc = exp2f(mold - m_run);
          float fcC[4];
#pragma unroll
          for (int reg = 0; reg < 4; ++reg) fcC[reg] = __shfl(fc, lg * 4 + reg);
#pragma unroll
          for (int reg = 0; reg < 4; ++reg) {
            l_acc[reg] *= fcC[reg];
#pragma unroll
            for (int dt = 0; dt < 4; ++dt) o[dt][reg] *= fcC[reg];
          }
        }

        // exp + packed P write (4 x ds_write_b64)
#pragma unroll
        for (int nt = 0; nt < 4; ++nt) {
          float p0 = exp2f(s[nt][0] - m_run);
          float p1 = exp2f(s[nt][1] - m_run);
          float p2 = exp2f(s[nt][2] - m_run);
          float p3 = exp2f(s[nt][3] - m_run);
          __hip_bfloat162 lo = __float22bfloat162_rn({p0, p1});
          __hip_bfloat162 hi = __float22bfloat162_rn({p2, p3});
          uint2 pk;
          pk.x = *reinterpret_cast<unsigned*>(&lo);
          pk.y = *reinterpret_cast<unsigned*>(&hi);
          *reinterpret_cast<uint2*>(pw + pwr[nt]) = pk;
        }

        // O += P @ V ; l += P @ 1
#pragma unroll
        for (int jc = 0; jc < 2; ++jc) {
          bf16x8 pf = *reinterpret_cast<const bf16x8*>(pw + pfa[jc]);
#pragma unroll
          for (int dt = 0; dt < 4; ++dt) {
            bf16x8 vf = *reinterpret_cast<const bf16x8*>(
                vb + (dt * 16 + lh) * 128 + (c0 ^ (jc << 6)));
            o[dt] = mfma16(pf, vf, o[dt]);
          }
          l_acc = mfma16(pf, ones, l_acc);
        }
      }
    }

    __syncthreads();
    cur ^= 1;
    kt = nkt;
  }

  // normalize + write y (text group: only waves 0,1 store)
  if (g != 12 || w < 2) {
#pragma unroll
    for (int reg = 0; reg < 4; ++reg) {
      int r = qt * 64 + wsub * 16 + lg * 4 + reg;
      if (r >= LSEQ) continue;
      float inv = 1.0f / l_acc[reg];
#pragma unroll
      for (int dt = 0; dt < 4; ++dt) {
        float v = o[dt][reg] * inv;
        yb[(size_t)(b * LSEQ + r) * CDIM + h * DHEAD + dt * 16 + lh] = f2bf(v);
      }
    }
  }
}

extern "C" void kernel_launch(void* const* d_in, const int* in_sizes, int n_in,
                              void* d_out, int out_size, void* d_ws, size_t ws_size,
                              hipStream_t stream) {
  (void)in_sizes; (void)n_in; (void)out_size;
  const float* x  = (const float*)d_in[0];
  const float* Wq = (const float*)d_in[1];
  const float* bq = (const float*)d_in[2];
  const float* Wk = (const float*)d_in[3];
  const float* bk = (const float*)d_in[4];
  const float* Wv = (const float*)d_in[5];
  const float* bv = (const float*)d_in[6];
  const float* Wp = (const float*)d_in[7];
  const float* bp = (const float*)d_in[8];
  const int* seg_s = (const int*)d_in[9];
  const int* seg_e = (const int*)d_in[10];

  const size_t NX = (size_t)MROWS * CDIM;  // 4,816,896
  const size_t NW = (size_t)CDIM * CDIM;   // 589,824
  const size_t need = (NX * 5 + NW * 4) * 2;
  if (ws_size < need) return;

  unsigned short* xb    = (unsigned short*)d_ws;
  unsigned short* wqkb  = xb + NX;          // [1536][768] (Wq rows, then Wk rows)
  unsigned short* wvb   = wqkb + 2 * NW;
  unsigned short* wpb   = wvb + NW;
  unsigned short* qkbuf = wpb + NW;         // [6272][1536]
  unsigned short* vtbuf = qkbuf + 2 * NX;   // [768][6272]
  unsigned short* ybuf  = vtbuf + NX;       // MUST follow vtbuf (tiny masked OOB reads land here)

  cvt5_kernel<<<(NX4 + 4 * NW4) / 256, 256, 0, stream>>>(x, Wq, Wk, Wv, Wp,
                                                         xb, wqkb, wvb, wpb);

  // Fused pre-attn GEMMs: Q|K projection (pre-scaled Q) + V^T projection
  gemm_pre<<<882, 256, 0, stream>>>(xb, wqkb, wvb, bq, bk, bv, qkbuf, vtbuf);

  attn_kernel<<<dim3(48, 13), 512, 0, stream>>>(qkbuf, vtbuf, ybuf, seg_s, seg_e);

  gemm_post<<<dim3(CDIM / 128, MROWS / 128), 256, 0, stream>>>(ybuf, wpb, bp, (float*)d_out);
}

// Round 9
// 116.465 us; speedup vs baseline: 2.8411x; 1.0918x over previous
//
#include <hip/hip_runtime.h>
#include <hip/hip_bf16.h>
#include <stdint.h>

typedef short bf16x8 __attribute__((ext_vector_type(8)));
typedef float f32x4 __attribute__((ext_vector_type(4)));

#define T_M   512
#define ML_   1536
#define LSEQ  1568
#define NHEAD 12
#define DHEAD 64
#define CDIM  768
#define NSEG  8
#define MROWS 6272  // B*L
#define CQK   1536  // q|k concat row stride
#define VTN   6272  // vt row length
#define NX4   1204224  // MROWS*CDIM/4
#define NW4   147456   // CDIM*CDIM/4
#define NWE   589824   // CDIM*CDIM
#define SCALE2 0.1803368801111244f  // 0.125 * log2(e)

__device__ __forceinline__ unsigned short f2bf(float f) {
  __hip_bfloat16 h = __float2bfloat16(f);
  return *reinterpret_cast<unsigned short*>(&h);
}

__device__ __forceinline__ void gll16(const void* g, void* l) {
  auto* lp = reinterpret_cast<__attribute__((address_space(3))) unsigned int*>(
      reinterpret_cast<uintptr_t>(l));
  auto* gp = reinterpret_cast<const __attribute__((address_space(1))) unsigned int*>(
      reinterpret_cast<uintptr_t>(g));
  __builtin_amdgcn_global_load_lds(gp, lp, 16, 0, 0);
}

__device__ __forceinline__ f32x4 mfma16(bf16x8 a, bf16x8 b, f32x4 c) {
  return __builtin_amdgcn_mfma_f32_16x16x32_bf16(a, b, c, 0, 0, 0);
}

// Single fused f32->bf16 convert for x, Wq, Wk, Wv, Wp.
__global__ __launch_bounds__(256) void cvt5_kernel(const float* __restrict__ x,
                                                   const float* __restrict__ wq,
                                                   const float* __restrict__ wk,
                                                   const float* __restrict__ wv,
                                                   const float* __restrict__ wp,
                                                   unsigned short* __restrict__ xb,
                                                   unsigned short* __restrict__ wqkb,
                                                   unsigned short* __restrict__ wvb,
                                                   unsigned short* __restrict__ wpb) {
  int gid = blockIdx.x * 256 + threadIdx.x;
  const float* src;
  unsigned short* dst;
  int idx;
  if (gid < NX4) {
    src = x; dst = xb; idx = gid;
  } else {
    int g = gid - NX4;
    int region = g / NW4;
    idx = g - region * NW4;
    if (region == 0)      { src = wq; dst = wqkb; }
    else if (region == 1) { src = wk; dst = wqkb + NWE; }
    else if (region == 2) { src = wv; dst = wvb; }
    else                  { src = wp; dst = wpb; }
  }
  float4 v = reinterpret_cast<const float4*>(src)[idx];
  __hip_bfloat162 lo = __float22bfloat162_rn({v.x, v.y});
  __hip_bfloat162 hi = __float22bfloat162_rn({v.z, v.w});
  uint2 st;
  st.x = *reinterpret_cast<unsigned*>(&lo);
  st.y = *reinterpret_cast<unsigned*>(&hi);
  reinterpret_cast<uint2*>(dst)[idx] = st;
}

// Shared GEMM body: C[m,n] = (sum_k A[m,k]*Bw[n,k] + bias) * colscale.
template <int OUT_BF16, int BIAS_ROW>
__device__ __forceinline__ void gemm_body(char* smem, int bx, int by,
                                          const unsigned short* __restrict__ A,
                                          const unsigned short* __restrict__ Bw,
                                          const float* __restrict__ bias0,
                                          const float* __restrict__ bias1, int bsplit,
                                          float sc0, float sc1,
                                          void* __restrict__ Cout,
                                          int M, int N, int K) {
  const int tid = threadIdx.x;
  const int lane = tid & 63;
  const int w = tid >> 6;
  const int m0 = by * 128, n0 = bx * 128;
  const int wr = (w >> 1) * 64, wc = (w & 1) * 64;

  unsigned gaoff[4], gboff[4];
#pragma unroll
  for (int it = 0; it < 4; ++it) {
    int off = it * 4096 + tid * 16;
    int r = off >> 7;
    int cb = (off & 127) ^ ((r & 7) << 4);
    gaoff[it] = (unsigned)((m0 + r) * K * 2 + cb);
    gboff[it] = (unsigned)((n0 + r) * K * 2 + cb);
  }
  const char* Ab = (const char*)A;
  const char* Bb = (const char*)Bw;

  f32x4 acc[4][4] = {};

  for (int ks = 0; ks < K; ks += 64) {
    __syncthreads();
#pragma unroll
    for (int it = 0; it < 4; ++it) {
      gll16(Ab + gaoff[it] + ks * 2, smem + it * 4096 + tid * 16);
      gll16(Bb + gboff[it] + ks * 2, smem + 16384 + it * 4096 + tid * 16);
    }
    __syncthreads();
#pragma unroll
    for (int kk = 0; kk < 2; ++kk) {
      const int cb = kk * 64 + (lane >> 4) * 16;
      bf16x8 av[4], bv[4];
#pragma unroll
      for (int mi = 0; mi < 4; ++mi) {
        int r = wr + mi * 16 + (lane & 15);
        av[mi] = *reinterpret_cast<const bf16x8*>(smem + r * 128 + (cb ^ ((r & 7) << 4)));
      }
#pragma unroll
      for (int ni = 0; ni < 4; ++ni) {
        int r = wc + ni * 16 + (lane & 15);
        bv[ni] = *reinterpret_cast<const bf16x8*>(smem + 16384 + r * 128 + (cb ^ ((r & 7) << 4)));
      }
#pragma unroll
      for (int mi = 0; mi < 4; ++mi)
#pragma unroll
        for (int ni = 0; ni < 4; ++ni)
          acc[mi][ni] = mfma16(av[mi], bv[ni], acc[mi][ni]);
    }
  }

#pragma unroll
  for (int mi = 0; mi < 4; ++mi) {
#pragma unroll
    for (int ni = 0; ni < 4; ++ni) {
      int col = n0 + wc + ni * 16 + (lane & 15);
      float bsc = BIAS_ROW ? 0.f : (col < bsplit ? bias0[col] : bias1[col - bsplit]);
      float scc = BIAS_ROW ? 1.f : (col < bsplit ? sc0 : sc1);
#pragma unroll
      for (int reg = 0; reg < 4; ++reg) {
        int row = m0 + wr + mi * 16 + (lane >> 4) * 4 + reg;
        float v = (acc[mi][ni][reg] + (BIAS_ROW ? bias0[row] : bsc)) * scc;
        if (OUT_BF16)
          ((unsigned short*)Cout)[(size_t)row * N + col] = f2bf(v);
        else
          ((float*)Cout)[(size_t)row * N + col] = v;
      }
    }
  }
}

// Fused pre-attention GEMMs: [0,588) = Q|K proj (12x49), [588,882) = V^T (49x6).
__global__ __launch_bounds__(256) void gemm_pre(const unsigned short* __restrict__ xb,
                                                const unsigned short* __restrict__ wqkb,
                                                const unsigned short* __restrict__ wvb,
                                                const float* __restrict__ bq,
                                                const float* __restrict__ bk,
                                                const float* __restrict__ bv,
                                                unsigned short* __restrict__ qkbuf,
                                                unsigned short* __restrict__ vtbuf) {
  __shared__ char smem[32768];
  int bid = blockIdx.x;
  if (bid < 588) {
    gemm_body<1, 0>(smem, bid % 12, bid / 12, xb, wqkb, bq, bk, 768, SCALE2, 1.0f,
                    qkbuf, MROWS, CQK, CDIM);
  } else {
    int b2 = bid - 588;
    gemm_body<1, 1>(smem, b2 % 49, b2 / 49, wvb, xb, bv, bv, 0, 1.0f, 1.0f,
                    vtbuf, CDIM, MROWS, CDIM);
  }
}

// Final projection GEMM.
__global__ __launch_bounds__(256) void gemm_post(const unsigned short* __restrict__ ybuf,
                                                 const unsigned short* __restrict__ wpb,
                                                 const float* __restrict__ bp,
                                                 float* __restrict__ out) {
  __shared__ char smem[32768];
  gemm_body<0, 0>(smem, blockIdx.x, blockIdx.y, ybuf, wpb, bp, bp, 1 << 30, 1.0f, 1.0f,
                  out, MROWS, CDIM, CDIM);
}

// LPT order of the 25 qt units, descending ceil(cnt/2).
__device__ const unsigned char qlpt[25] = {
    15, 23, 24, 14, 22, 13, 21, 12, 20, 11, 19, 10, 18,
    9, 17, 7, 6, 5, 4, 8, 16, 3, 2, 1, 0};

// next included KV-tile after kt for this qt
__device__ __forceinline__ int step_kt(int kt, int rb, int qtl) {
  if (rb == 0 || rb == 3) return kt + 1;
  if ((kt & 7) < qtl) return kt + 1;
  if (kt < 16) return (kt & ~7) + 8;
  return 24;
}

// Flash attention: per-qt blocks, 2-way split-KV inside the block, LDS K/V
// sharing, swapped QK^T lane-local softmax, in-block split merge.
// Block = 512 threads = 8 waves: wave w -> q-subtile (w&3), KV-half (w>>2).
// Each iteration stages BOTH halves' tiles (2x16KB, single-buffered), then each
// half computes its own tile. After the loop the two halves' (m,l,O) merge via
// LDS (reusing the staging region). Max chain 25 -> 13 iterations.
// qk: [6272][1536] bf16 (q cols 0..767 PRE-SCALED by 0.125*log2e, k 768..1535)
// vt: [768][6272] bf16  (row = h*64+d, col = b*1568+j)
// Grid: (48 bh, 25 qt-rank), 512 threads.
__global__ __launch_bounds__(512) void attn_kernel(const unsigned short* __restrict__ qk,
                                                   const unsigned short* __restrict__ vt,
                                                   unsigned short* __restrict__ yb,
                                                   const int* __restrict__ seg_s,
                                                   const int* __restrict__ seg_e) {
  __shared__ char smem[49664];  // [2 tiles][K 8KB|V 8KB] + P[8][2KB] + m/l 512B
  const int tid = threadIdx.x;
  const int lane = tid & 63;
  const int w = tid >> 6;
  const int lh = lane & 15, lg = lane >> 4;
  const int bh = blockIdx.x;
  const int b = bh / NHEAD, h = bh % NHEAD;
  const int qt = qlpt[blockIdx.y];
  const int wsub = w & 3;
  const int half = w >> 2;
  const int rb_q = qt >> 3;   // 0,1,2 motion; 3 text
  const int qtl = qt & 7;
  const int cnt = (rb_q == 0) ? (qtl + 1) : (rb_q < 3 ? 3 * (qtl + 1) + 1 : 25);
  char* pw = smem + 32768 + w * 2048;

  // Q fragments (pre-scaled into log2 domain); MFMA B-operand.
  int qr = qt * 64 + wsub * 16 + lh;
  if (qr >= LSEQ) qr = LSEQ - 1;
  const unsigned short* qp = qk + ((size_t)(b * LSEQ + qr) * CQK + h * DHEAD + lg * 8);
  const bf16x8 qf0 = *reinterpret_cast<const bf16x8*>(qp);
  const bf16x8 qf1 = *reinterpret_cast<const bf16x8*>(qp + 32);

  const char* qkc = (const char*)qk + (size_t)b * LSEQ * CQK * 2;
  const char* vtc = (const char*)vt + (size_t)b * LSEQ * 2;

  // staging precompute (waves 0-3: K rows, waves 4-7: V rows; both tiles)
  const int cbyte = (((lane & 7) ^ (lane >> 3)) << 4);
  const int rlA = (w & 3) * 16 + (lane >> 3);
  const char* kqbase = qkc + (768 + h * DHEAD) * 2 + cbyte;
  size_t vbo[2];
#pragma unroll
  for (int t = 0; t < 2; ++t)
    vbo[t] = (size_t)(h * DHEAD + rlA + t * 8) * (VTN * 2) + cbyte;

  const int c0 = (lg * 16) ^ ((lh & 7) << 4);

  // loop-invariant mask data (swapped layout: lane q = lh; k = nt*16+lg*4+reg)
  const int f_lane = (qt * 64 + wsub * 16 + lh) & 511;
  float a_k[4];
#pragma unroll
  for (int nt = 0; nt < 4; ++nt) {
    int j = nt * 2 + (lg >> 1);
    bool st = (rb_q == 3) || ((rb_q == 1) ? (j != 1) : (j != 0));
    a_k[nt] = (nt < 2 && st) ? 0.f : -1e30f;
  }
  float w4[4];
#pragma unroll
  for (int reg = 0; reg < 4; ++reg) {
    int ii = (lg * 4 + reg) & 7;
    int ssv = seg_s[b * NSEG + ii], sev = seg_e[b * NSEG + ii];
    w4[reg] = (rb_q == 3) ? 0.f : ((f_lane >= ssv && f_lane < sev) ? 0.f : -1e30f);
  }

  // P LDS addresses
  int pfa[2];
#pragma unroll
  for (int jc = 0; jc < 2; ++jc)
    pfa[jc] = lh * 128 + (((jc * 32 + lg * 8) * 2) ^ ((lh & 7) << 4));
  int pwr[4];
#pragma unroll
  for (int nt = 0; nt < 4; ++nt)
    pwr[nt] = lh * 128 + ((nt * 32 + lg * 8) ^ ((lh & 7) << 4));

  const short oneb = (short)0x3F80;
  const bf16x8 ones = {oneb, oneb, oneb, oneb, oneb, oneb, oneb, oneb};

  f32x4 o[4] = {};
  f32x4 l_acc = {};
  float m_run = -1e30f;  // per-lane (q = lh), log2 domain

  int ktA = 0;
  int ktB = step_kt(0, rb_q, qtl);
  if (ktB > 24) ktB = 24;
  const int niter = (cnt + 1) >> 1;

  for (int j = 0; j < niter; ++j) {
    __syncthreads();  // previous pair fully consumed

    // stage both halves' tiles (single-buffered)
    int kts0 = ktA, kts1 = ktB;
#pragma unroll
    for (int q = 0; q < 2; ++q) {
      int kt = q ? kts1 : kts0;
#pragma unroll
      for (int t = 0; t < 2; ++t) {
        char* dst = smem + q * 16384 + (w < 4 ? 0 : 8192) + (2 * (w & 3) + t) * 1024 +
                    lane * 16;
        const char* src;
        if (w < 4) {
          int gr = kt * 64 + rlA + t * 8;
          if (gr > LSEQ - 1) gr = LSEQ - 1;
          src = kqbase + (size_t)gr * (CQK * 2);
        } else {
          src = vtc + vbo[t] + (size_t)kt * 128;
        }
        gll16(src, dst);
      }
    }
    __syncthreads();  // staged (compiler drains vmcnt)

    const int myidx = 2 * j + half;
    if (myidx < cnt) {
      const int kt = half ? ktB : ktA;
      const char* kb = smem + half * 16384;
      const char* vb = kb + 8192;

      // S^T = K Q^T : s[nt][reg] = S[q=lh][k = nt*16 + lg*4 + reg]
      f32x4 s[4];
#pragma unroll
      for (int nt = 0; nt < 4; ++nt) {
        const char* kr = kb + (nt * 16 + lh) * 128;
        bf16x8 k0 = *reinterpret_cast<const bf16x8*>(kr + c0);
        bf16x8 k1 = *reinterpret_cast<const bf16x8*>(kr + (c0 ^ 64));
        f32x4 z = {};
        z = mfma16(k0, qf0, z);
        z = mfma16(k1, qf1, z);
        s[nt] = z;
      }

      // mask
      if (kt == 24) {
#pragma unroll
        for (int nt = 0; nt < 4; ++nt)
#pragma unroll
          for (int reg = 0; reg < 4; ++reg)
            s[nt][reg] += a_k[nt] + w4[reg];
      } else if (rb_q < 3 && (kt & 7) == qtl) {
        const int cbk = kt >> 3;
        const bool strict = (rb_q == 1) ? (cbk != 0) : ((rb_q == 2) ? (cbk == 2) : false);
        const int dbase = qtl * 64 + lg * 4;
#pragma unroll
        for (int nt = 0; nt < 4; ++nt)
#pragma unroll
          for (int reg = 0; reg < 4; ++reg) {
            int kcol = dbase + nt * 16 + reg;
            bool ok = strict ? (kcol < f_lane) : (kcol <= f_lane);
            s[nt][reg] = ok ? s[nt][reg] : -1e30f;
          }
      }

      // lane-local row max + 2 cross-lg shfl steps
      float mt = s[0][0];
#pragma unroll
      for (int nt = 0; nt < 4; ++nt)
#pragma unroll
        for (int reg = 0; reg < 4; ++reg)
          if (nt || reg) mt = fmaxf(mt, s[nt][reg]);
      mt = fmaxf(mt, __shfl_xor(mt, 16));
      mt = fmaxf(mt, __shfl_xor(mt, 32));

      if (!__all(mt <= -1e29f)) {
        if (!__all(mt <= m_run + 12.f)) {
          float mold = m_run;
          m_run = fmaxf(m_run, mt);
          float fc = exp2f(mold - m_run);
          float fcC[4];
#pragma unroll
          for (int reg = 0; reg < 4; ++reg) fcC[reg] = __shfl(fc, lg * 4 + reg);
#pragma unroll
          for (int reg = 0; reg < 4; ++reg) {
            l_acc[reg] *= fcC[reg];
#pragma unroll
            for (int dt = 0; dt < 4; ++dt) o[dt][reg] *= fcC[reg];
          }
        }

        // exp + packed P write (4 x ds_write_b64)
#pragma unroll
        for (int nt = 0; nt < 4; ++nt) {
          float p0 = exp2f(s[nt][0] - m_run);
          float p1 = exp2f(s[nt][1] - m_run);
          float p2 = exp2f(s[nt][2] - m_run);
          float p3 = exp2f(s[nt][3] - m_run);
          __hip_bfloat162 lo = __float22bfloat162_rn({p0, p1});
          __hip_bfloat162 hi = __float22bfloat162_rn({p2, p3});
          uint2 pk;
          pk.x = *reinterpret_cast<unsigned*>(&lo);
          pk.y = *reinterpret_cast<unsigned*>(&hi);
          *reinterpret_cast<uint2*>(pw + pwr[nt]) = pk;
        }

        // O += P @ V ; l += P @ 1
#pragma unroll
        for (int jc = 0; jc < 2; ++jc) {
          bf16x8 pf = *reinterpret_cast<const bf16x8*>(pw + pfa[jc]);
#pragma unroll
          for (int dt = 0; dt < 4; ++dt) {
            bf16x8 vf = *reinterpret_cast<const bf16x8*>(
                vb + (dt * 16 + lh) * 128 + (c0 ^ (jc << 6)));
            o[dt] = mfma16(pf, vf, o[dt]);
          }
          l_acc = mfma16(pf, ones, l_acc);
        }
      }
    }

    // advance both halves' tiles by 2 positions
    ktA = step_kt(ktB, rb_q, qtl);
    if (ktA > 24) ktA = 24;
    ktB = step_kt(ktA, rb_q, qtl);
    if (ktB > 24) ktB = 24;
  }

  // ---- merge the two KV-halves (reuse staging LDS) ----
  float* olds = (float*)smem;                 // [4][16][64] f32 = 16KB
  float* mf = (float*)(smem + 16384);         // [4][16]
  float* lf = (float*)(smem + 16384 + 256);   // [4][16]
  __syncthreads();
  if (half == 0) {
#pragma unroll
    for (int reg = 0; reg < 4; ++reg) {
#pragma unroll
      for (int dt = 0; dt < 4; ++dt)
        olds[(wsub * 16 + lg * 4 + reg) * 64 + dt * 16 + lh] = o[dt][reg];
      if (lh == 0) lf[wsub * 16 + lg * 4 + reg] = l_acc[reg];
    }
    if (lg == 0) mf[wsub * 16 + lh] = m_run;
  }
  __syncthreads();
  if (half == 1) {
#pragma unroll
    for (int reg = 0; reg < 4; ++reg) {
      int row = lg * 4 + reg;
      int r = qt * 64 + wsub * 16 + row;
      if (r >= LSEQ) continue;
      float m1 = mf[wsub * 16 + row];
      float l1 = lf[wsub * 16 + row];
      float m2 = __shfl(m_run, row);
      float M = fmaxf(m1, m2);
      float w1 = exp2f(m1 - M);
      float w2 = exp2f(m2 - M);
      float inv = 1.0f / (l1 * w1 + l_acc[reg] * w2);
#pragma unroll
      for (int dt = 0; dt < 4; ++dt) {
        int col = dt * 16 + lh;
        float v = (olds[(wsub * 16 + row) * 64 + col] * w1 + o[dt][reg] * w2) * inv;
        yb[(size_t)(b * LSEQ + r) * CDIM + h * DHEAD + col] = f2bf(v);
      }
    }
  }
}

extern "C" void kernel_launch(void* const* d_in, const int* in_sizes, int n_in,
                              void* d_out, int out_size, void* d_ws, size_t ws_size,
                              hipStream_t stream) {
  (void)in_sizes; (void)n_in; (void)out_size;
  const float* x  = (const float*)d_in[0];
  const float* Wq = (const float*)d_in[1];
  const float* bq = (const float*)d_in[2];
  const float* Wk = (const float*)d_in[3];
  const float* bk = (const float*)d_in[4];
  const float* Wv = (const float*)d_in[5];
  const float* bv = (const float*)d_in[6];
  const float* Wp = (const float*)d_in[7];
  const float* bp = (const float*)d_in[8];
  const int* seg_s = (const int*)d_in[9];
  const int* seg_e = (const int*)d_in[10];

  const size_t NX = (size_t)MROWS * CDIM;  // 4,816,896
  const size_t NW = (size_t)CDIM * CDIM;   // 589,824
  const size_t need = (NX * 5 + NW * 4) * 2;
  if (ws_size < need) return;

  unsigned short* xb    = (unsigned short*)d_ws;
  unsigned short* wqkb  = xb + NX;          // [1536][768] (Wq rows, then Wk rows)
  unsigned short* wvb   = wqkb + 2 * NW;
  unsigned short* wpb   = wvb + NW;
  unsigned short* qkbuf = wpb + NW;         // [6272][1536]
  unsigned short* vtbuf = qkbuf + 2 * NX;   // [768][6272]
  unsigned short* ybuf  = vtbuf + NX;       // MUST follow vtbuf (tiny masked OOB reads land here)

  cvt5_kernel<<<(NX4 + 4 * NW4) / 256, 256, 0, stream>>>(x, Wq, Wk, Wv, Wp,
                                                         xb, wqkb, wvb, wpb);

  gemm_pre<<<882, 256, 0, stream>>>(xb, wqkb, wvb, bq, bk, bv, qkbuf, vtbuf);

  attn_kernel<<<dim3(48, 25), 512, 0, stream>>>(qkbuf, vtbuf, ybuf, seg_s, seg_e);

  gemm_post<<<dim3(CDIM / 128, MROWS / 128), 256, 0, stream>>>(ybuf, wpb, bp, (float*)d_out);
}